// Round 10
// baseline (590.805 us; speedup 1.0000x reference)
//
#include <hip/hip_runtime.h>
#include <hip/hip_bf16.h>
#include <stdint.h>

typedef __bf16 bf16x8 __attribute__((ext_vector_type(8)));
typedef float  f32x4  __attribute__((ext_vector_type(4)));
typedef float  vf4    __attribute__((ext_vector_type(4)));
typedef unsigned int vu4 __attribute__((ext_vector_type(4)));

#define DEV __device__ __forceinline__

constexpr int SUBJ  = 4;
constexpr int IN    = 4096;
constexpr int H     = 2048;
constexpr int DEPTH = 6;
constexpr int BATCH = 1024;
constexpr int BOT   = 128;
constexpr int IMG   = 768;
constexpr int TXT   = 768;
constexpr int MP    = 1408;   // padded sorted rows
constexpr int MT    = 11;     // MP/128 row tiles

DEV float gelu_exact(float x){ return 0.5f*x*(1.0f + erff(x*0.70710678118654752440f)); }

DEV uint32_t pk_bf16(float a, float b){
  __hip_bfloat16 ha = __float2bfloat16(a), hb = __float2bfloat16(b);
  return (uint32_t)*reinterpret_cast<uint16_t*>(&ha)
       | ((uint32_t)*reinterpret_cast<uint16_t*>(&hb) << 16);
}

DEV void nt_store_f(float* p, float v){ __builtin_nontemporal_store(v, p); }
DEV void nt_store_bf(__hip_bfloat16* p, float v){
  __hip_bfloat16 h = __float2bfloat16(v);
  __builtin_nontemporal_store(*reinterpret_cast<uint16_t*>(&h), reinterpret_cast<uint16_t*>(p));
}
DEV void nt_store_f4(float* p, float4 v){
  vf4 x = {v.x, v.y, v.z, v.w};
  __builtin_nontemporal_store(x, reinterpret_cast<vf4*>(p));
}
DEV void nt_store_u4(void* p, vu4 v){
  __builtin_nontemporal_store(v, reinterpret_cast<vu4*>(p));
}

// raw barrier: drain ONLY lgkm (LDS) — outstanding global loads stay in flight.
DEV void block_sync(){
  asm volatile("s_waitcnt lgkmcnt(0)" ::: "memory");
  __builtin_amdgcn_s_barrier();
  asm volatile("" ::: "memory");
}

// ---------------- subject counting-sort (1 block, 1024 threads) ----------------
__global__ void sort_kernel(const int* __restrict__ ids, int* __restrict__ rowmap,
                            int* __restrict__ tileS){
  __shared__ int hist[16][4];
  __shared__ int basew[16][4];
  __shared__ int pstart[5];
  int tid = threadIdx.x;
  if (tid < MP) rowmap[tid] = -1;
  if (tid + 1024 < MP) rowmap[tid + 1024] = -1;
  int w = tid >> 6, lane = tid & 63;
  int my = ids[tid];
  unsigned long long mymask = 0ull;
  #pragma unroll
  for (int s = 0; s < 4; ++s){
    unsigned long long m = __ballot(my == s);
    if (lane == 0) hist[w][s] = (int)__popcll(m);
    if (s == my) mymask = m;
  }
  int myrank = (int)__popcll(mymask & ((1ull << lane) - 1ull));
  __syncthreads();
  if (tid == 0){
    for (int s = 0; s < 4; ++s){
      int run = 0;
      for (int ww = 0; ww < 16; ++ww){ basew[ww][s] = run; run += hist[ww][s]; }
      hist[0][s] = run;
    }
    pstart[0] = 0;
    for (int s = 0; s < 4; ++s) pstart[s+1] = pstart[s] + ((hist[0][s] + 127) & ~127);
  }
  __syncthreads();
  int pos = pstart[my] + basew[w][my] + myrank;
  rowmap[pos] = tid;
  if (tid < MT){
    int row0 = tid << 7, s = -1;
    for (int ss = 0; ss < 4; ++ss) if (row0 >= pstart[ss] && row0 < pstart[ss+1]) s = ss;
    tileS[tid] = s;
  }
}

// ---------------- gather voxels into sorted order, fp32 -> bf16 ----------------
__global__ void gather_voxels(const float* __restrict__ vox, const int* __restrict__ rowmap,
                              __hip_bfloat16* __restrict__ Vs){
  int r = blockIdx.x, tid = threadIdx.x;
  int orig = rowmap[r];
  #pragma unroll
  for (int i = 0; i < 4; ++i){
    int c = (i*256 + tid) << 2;
    float4 v = {0.f,0.f,0.f,0.f};
    if (orig >= 0) v = *reinterpret_cast<const float4*>(vox + (size_t)orig*IN + c);
    __hip_bfloat16 o[4] = {__float2bfloat16(v.x), __float2bfloat16(v.y),
                           __float2bfloat16(v.z), __float2bfloat16(v.w)};
    *reinterpret_cast<uint2*>(Vs + (size_t)r*IN + c) = *reinterpret_cast<const uint2*>(o);
  }
}

// ---------------- 128x128 MFMA GEMM, BK=64, reg-staged depth-2 pipeline --------------
// All staging goes global->reg->LDS. Depth-2 prefetch: loads for tile t+2 issued while
// computing tile t; the ds_write of tile t+1 triggers a compiler-counted vmcnt wait
// (loads are a full iteration old -> latency hidden; 12 newer loads stay in flight).
// Raw barrier drains lgkm only -> vmcnt NEVER drains to 0 (the R5-R9 duty-cycle stall).
// One barrier per K-step (was two).
enum { EPI_SPLIT = 0, EPI_RES_BF16 = 1, EPI_HEADS = 3 };

template<int EPI>
__global__ __launch_bounds__(256, 2)
void gemm_bf16(const __hip_bfloat16* __restrict__ A, int lda,
               const float* __restrict__ Bw, int ldn, long long wsub,
               const int* __restrict__ tileS, const int* __restrict__ rowmap,
               int nx, int ksplit,
               const float* __restrict__ bias, int biassub,
               const float* __restrict__ resid, int ldres,
               float* __restrict__ outf, __hip_bfloat16* __restrict__ outb, int ldo,
               size_t pstride, const float* __restrict__ Bw2)
{
  int b   = blockIdx.x;
  int xcd = b & 7;
  int r0  = b >> 3;
  int mt  = r0 % MT;
  int q   = r0 / MT;
  int kzi = xcd / nx;
  int nt  = q * nx + (xcd % nx);

  int s = tileS[mt];
  if (s < 0) return;                       // inactive (pad) row tile
  const __hip_bfloat16* Ab = A + (size_t)mt*128*lda;

  const float* Bb;
  int ntl = nt;
  if constexpr (EPI == EPI_HEADS){
    if (nt < 6){ Bb = Bw  + (size_t)nt*128; }
    else       { Bb = Bw2 + (size_t)(nt-6)*128; }
    ntl = nt;                              // col in concat [0,1536)
  } else {
    Bb = Bw + (size_t)s*wsub + (size_t)nt*128;
  }

  int kb = kzi * ksplit;
  int nk = ksplit >> 6;                    // even for all call sites (2,8,16)

  __shared__ __hip_bfloat16 sA[2][128*64];
  __shared__ __hip_bfloat16 sB[2][128*64];

  int tid = threadIdx.x;
  int lane = tid & 63;
  int wv = tid >> 6, wr = wv >> 1, wc = wv & 1;

  int kq = tid >> 5;                       // B staging: 8 k-rows x 4 n-cols per thread
  int nq = tid & 31;
  int n4 = nq << 2;

  f32x4 acc[4][4];
  #pragma unroll
  for (int i = 0; i < 4; ++i)
    #pragma unroll
    for (int j = 0; j < 4; ++j) acc[i][j] = (f32x4){0.f,0.f,0.f,0.f};

  // ---- staging helpers (linear global reads; swizzle applied on LDS write) ----
  auto loadA = [&](int k0, uint4* FA){
    #pragma unroll
    for (int i = 0; i < 4; ++i){
      int c = i*256 + tid;
      int row = c >> 3, cc = c & 7;
      FA[i] = *reinterpret_cast<const uint4*>(Ab + (size_t)row*lda + k0 + (cc<<3));
    }
  };
  auto writeA = [&](int buf, const uint4* FA){
    #pragma unroll
    for (int i = 0; i < 4; ++i){
      int c = i*256 + tid;
      int row = c >> 3, cc = c & 7;
      int cs = cc ^ (row & 7);
      *reinterpret_cast<uint4*>(&sA[buf][(row<<6) + (cs<<3)]) = FA[i];
    }
  };
  auto loadB = [&](int k0, float4* F){
    const float* p = Bb + (size_t)(k0 + (kq<<3))*ldn + n4;
    #pragma unroll
    for (int rr = 0; rr < 8; ++rr)
      F[rr] = *reinterpret_cast<const float4*>(p + (size_t)rr*ldn);
  };
  auto writeB = [&](int buf, const float4* F){
    #pragma unroll
    for (int j = 0; j < 4; ++j){
      int n = n4 + j;
      int cell = (kq ^ (n >> 3) ^ n) & 7;
      uint4 d;
      d.x = pk_bf16(((const float*)&F[0])[j], ((const float*)&F[1])[j]);
      d.y = pk_bf16(((const float*)&F[2])[j], ((const float*)&F[3])[j]);
      d.z = pk_bf16(((const float*)&F[4])[j], ((const float*)&F[5])[j]);
      d.w = pk_bf16(((const float*)&F[6])[j], ((const float*)&F[7])[j]);
      *reinterpret_cast<uint4*>(&sB[buf][(n<<6) + (cell<<3)]) = d;
    }
  };
  auto compute = [&](const __hip_bfloat16* bA, const __hip_bfloat16* bB){
    const char* baseA = (const char*)bA;
    const char* baseB = (const char*)bB;
    int rA = (wr<<6) + (lane & 15);
    int rB = (wc<<6) + (lane & 15);
    #pragma unroll
    for (int kk = 0; kk < 2; ++kk){
      int koffA = ((((kk<<5) + ((lane>>4)<<3)) << 1)) ^ ((lane & 7) << 4);
      bf16x8 av[4], bv[4];
      #pragma unroll
      for (int f = 0; f < 4; ++f){
        int rowA = rA + f*16;
        av[f] = *reinterpret_cast<const bf16x8*>(baseA + (size_t)rowA*128 + koffA);
        int rowB = rB + f*16;
        int cellB = (((kk<<2) + (lane>>4)) ^ (rowB >> 3) ^ rowB) & 7;
        bv[f] = *reinterpret_cast<const bf16x8*>(baseB + (size_t)rowB*128 + (cellB<<4));
      }
      #pragma unroll
      for (int i = 0; i < 4; ++i)
        #pragma unroll
        for (int j = 0; j < 4; ++j)
          acc[i][j] = __builtin_amdgcn_mfma_f32_16x16x32_bf16(av[i], bv[j], acc[i][j], 0, 0, 0);
    }
  };
  auto kof = [&](int t)->int{ int tt = t < nk ? t : nk-1; return kb + (tt<<6); };

  // ---- prologue: tiles 0 and 1 in flight; tile 0 written ----
  uint4  FA0[4], FA1[4];
  float4 FB0[8], FB1[8];
  loadA(kof(0), FA0); loadB(kof(0), FB0);
  loadA(kof(1), FA1); loadB(kof(1), FB1);
  writeA(0, FA0); writeB(0, FB0);          // compiler waits exactly for tile-0 loads
  block_sync();

  // ---- steady loop: 2 tiles per trip; one barrier per tile; vmcnt never 0 ----
  for (int t = 0; t < nk; t += 2){
    loadA(kof(t+2), FA0); loadB(kof(t+2), FB0);   // depth-2 prefetch (slot0)
    compute(sA[0], sB[0]);                         // tile t
    writeA(1, FA1); writeB(1, FB1);                // tile t+1 -> buf1 (counted wait)
    block_sync();
    loadA(kof(t+3), FA1); loadB(kof(t+3), FB1);   // depth-2 prefetch (slot1)
    compute(sA[1], sB[1]);                         // tile t+1
    writeA(0, FA0); writeB(0, FB0);                // tile t+2 -> buf0
    block_sync();
  }

  // epilogue; C/D layout (m89-verified): col = lane&15, row = (lane>>4)*4 + reg.
  #pragma unroll
  for (int i = 0; i < 4; ++i){
    int rbase = (mt<<7) + (wr<<6) + (i<<4) + ((lane>>4)<<2);
    #pragma unroll
    for (int j = 0; j < 4; ++j){
      int colp = (wc<<6) + (j<<4) + (lane & 15);
      #pragma unroll
      for (int qq = 0; qq < 4; ++qq){
        int r = rbase + qq;
        float v = acc[i][j][qq];
        if constexpr (EPI == EPI_SPLIT){
          int col = (nt<<7) + colp;
          nt_store_f(outf + (size_t)kzi*pstride + (size_t)r*ldo + col, v);
        } else if constexpr (EPI == EPI_RES_BF16){
          int col = (nt<<7) + colp;
          int orig = rowmap[r];
          if (orig >= 0){
            v += bias[(size_t)s*biassub + col] + resid[(size_t)orig*ldres + col];
            nt_store_bf(outb + (size_t)r*ldo + col, v);
          }
        } else { // EPI_HEADS
          int col = (ntl<<7) + colp;
          nt_store_f(outf + (size_t)kzi*pstride + (size_t)r*ldo + col, v);
        }
      }
    }
  }
}

// ---------------- T1 = gelu(sum_p T1p + db[s])  (bf16) ----------------
__global__ void t1_epilogue(const float* __restrict__ Tp, const float* __restrict__ db,
                            const int* __restrict__ rowmap, const int* __restrict__ tileS,
                            __hip_bfloat16* __restrict__ T1){
  int idx = blockIdx.x*256 + threadIdx.x;
  int r = idx >> 7, c = idx & 127;
  float v = 0.f;
  if (rowmap[r] >= 0){
    int s = tileS[r >> 7];
    float acc = 0.f;
    #pragma unroll
    for (int p = 0; p < 8; ++p) acc += Tp[(size_t)p*MP*BOT + idx];
    v = gelu_exact(acc + db[s*BOT + c]);
  }
  T1[idx] = __float2bfloat16(v);
}

// ---------------- row LN over summed partials (+linear bias) + gelu (+residual) ------
template<int RES, int NPART>
__global__ void ln_gelu_kernel(const float* __restrict__ Zp, size_t pstride,
                               const float* __restrict__ g,
                               const float* __restrict__ b, int gsub,
                               const float* __restrict__ lb,
                               const int* __restrict__ tileS, const int* __restrict__ rowmap,
                               float* __restrict__ Xf, __hip_bfloat16* __restrict__ Xb){
  int r = blockIdx.x, tid = threadIdx.x;
  size_t rowoff = (size_t)r * H;
  int c0 = tid << 3;
  int orig = rowmap[r];
  if (orig < 0){
    float4 zf = {0.f,0.f,0.f,0.f};
    nt_store_f4(Xf + rowoff + c0, zf);
    nt_store_f4(Xf + rowoff + c0 + 4, zf);
    vu4 zu = {0u,0u,0u,0u};
    nt_store_u4(Xb + rowoff + c0, zu);
    return;
  }
  int si = gsub ? tileS[r>>7] : 0;
  const float* gp  = g  + (size_t)si*gsub;
  const float* bp  = b  + (size_t)si*gsub;
  const float* lbp = lb + (size_t)si*gsub;
  float z[8];
  #pragma unroll
  for (int j = 0; j < 8; ++j) z[j] = lbp[c0+j];
  #pragma unroll
  for (int p = 0; p < NPART; ++p){
    float4 v1 = *reinterpret_cast<const float4*>(Zp + p*pstride + rowoff + c0);
    float4 v2 = *reinterpret_cast<const float4*>(Zp + p*pstride + rowoff + c0 + 4);
    z[0]+=v1.x; z[1]+=v1.y; z[2]+=v1.z; z[3]+=v1.w;
    z[4]+=v2.x; z[5]+=v2.y; z[6]+=v2.z; z[7]+=v2.w;
  }
  float s1 = 0.f, s2 = 0.f;
  #pragma unroll
  for (int j = 0; j < 8; ++j){ s1 += z[j]; s2 += z[j]*z[j]; }
  #pragma unroll
  for (int m = 32; m >= 1; m >>= 1){ s1 += __shfl_xor(s1, m); s2 += __shfl_xor(s2, m); }
  __shared__ float red[4][2];
  int wv = tid >> 6, lane = tid & 63;
  if (lane == 0){ red[wv][0] = s1; red[wv][1] = s2; }
  __syncthreads();
  s1 = red[0][0]+red[1][0]+red[2][0]+red[3][0];
  s2 = red[0][1]+red[1][1]+red[2][1]+red[3][1];
  const float invH = 1.f / (float)H;
  float mu  = s1 * invH;
  float var = s2 * invH - mu*mu;
  float rs  = rsqrtf(var + 1e-5f);
  float o[8];
  #pragma unroll
  for (int j = 0; j < 8; ++j){
    float t = (z[j]-mu)*rs*gp[c0+j] + bp[c0+j];
    o[j] = gelu_exact(t);
  }
  if constexpr (RES){
    float4 x1 = *reinterpret_cast<const float4*>(Xf + rowoff + c0);
    float4 x2 = *reinterpret_cast<const float4*>(Xf + rowoff + c0 + 4);
    o[0]+=x1.x; o[1]+=x1.y; o[2]+=x1.z; o[3]+=x1.w;
    o[4]+=x2.x; o[5]+=x2.y; o[6]+=x2.z; o[7]+=x2.w;
  }
  float4 w1 = {o[0],o[1],o[2],o[3]}, w2 = {o[4],o[5],o[6],o[7]};
  nt_store_f4(Xf + rowoff + c0, w1);
  nt_store_f4(Xf + rowoff + c0 + 4, w2);
  __hip_bfloat16 ob[8];
  #pragma unroll
  for (int j = 0; j < 8; ++j) ob[j] = __float2bfloat16(o[j]);
  nt_store_u4(Xb + rowoff + c0, *reinterpret_cast<const vu4*>(ob));
}

// ---------------- heads combine: sum 2 partials + bias, scatter to original rows ------
__global__ void head_combine(const float* __restrict__ Hp, size_t pstride,
                             const float* __restrict__ img_b, const float* __restrict__ txt_b,
                             const int* __restrict__ rowmap,
                             float* __restrict__ oimg, float* __restrict__ otxt){
  int r = blockIdx.x;
  int orig = rowmap[r];
  if (orig < 0) return;
  int col = threadIdx.x << 2;                    // 384 threads x 4 cols = 1536
  size_t base = (size_t)r*(IMG+TXT) + col;
  float4 v0 = *reinterpret_cast<const float4*>(Hp + base);
  float4 v1 = *reinterpret_cast<const float4*>(Hp + pstride + base);
  float4 bb = (col < IMG)
            ? *reinterpret_cast<const float4*>(img_b + col)
            : *reinterpret_cast<const float4*>(txt_b + (col - IMG));
  float4 o = {v0.x+v1.x+bb.x, v0.y+v1.y+bb.y, v0.z+v1.z+bb.z, v0.w+v1.w+bb.w};
  if (col < IMG) nt_store_f4(oimg + (size_t)orig*IMG + col, o);
  else           nt_store_f4(otxt + (size_t)orig*TXT + (col-IMG), o);
}

// ------------------------------------------------------------------------------
extern "C" void kernel_launch(void* const* d_in, const int* in_sizes, int n_in,
                              void* d_out, int out_size, void* d_ws, size_t ws_size,
                              hipStream_t stream){
  (void)in_sizes; (void)n_in; (void)out_size; (void)ws_size;
  const float* vox       = (const float*)d_in[0];
  const int*   ids       = (const int*)  d_in[1];
  const float* ad_down_w = (const float*)d_in[2];
  const float* ad_down_b = (const float*)d_in[3];
  const float* ad_up_w   = (const float*)d_in[4];
  const float* ad_up_b   = (const float*)d_in[5];
  const float* enc_w     = (const float*)d_in[6];
  const float* enc_b     = (const float*)d_in[7];
  const float* enc_ln_g  = (const float*)d_in[8];
  const float* enc_ln_bb = (const float*)d_in[9];
  const float* bb_w      = (const float*)d_in[10];
  const float* bb_b      = (const float*)d_in[11];
  const float* bb_ln_g   = (const float*)d_in[12];
  const float* bb_ln_b   = (const float*)d_in[13];
  const float* img_w     = (const float*)d_in[14];
  const float* img_b     = (const float*)d_in[15];
  const float* txt_w     = (const float*)d_in[16];
  const float* txt_b     = (const float*)d_in[17];
  float* out = (float*)d_out;

  char* wp = (char*)d_ws;
  auto alloc = [&](size_t bytes)->char*{ char* p = wp; wp += (bytes + 255) & ~(size_t)255; return p; };
  int* rowmap = (int*)alloc(MP * sizeof(int));
  int* tileS  = (int*)alloc(MT * sizeof(int));
  __hip_bfloat16* Vs    = (__hip_bfloat16*)alloc((size_t)MP*IN*2);
  float* T1p            = (float*)alloc((size_t)8*MP*BOT*4);
  __hip_bfloat16* T1    = (__hip_bfloat16*)alloc((size_t)MP*BOT*2);
  __hip_bfloat16* Hs    = (__hip_bfloat16*)alloc((size_t)MP*IN*2);
  float* Zp             = (float*)alloc((size_t)4*MP*H*4);
  float* Hp             = (float*)alloc((size_t)2*MP*(IMG+TXT)*4);
  float* Xf             = (float*)alloc((size_t)MP*H*4);
  __hip_bfloat16* Xb    = (__hip_bfloat16*)alloc((size_t)MP*H*2);

  const size_t ZPS = (size_t)MP*H;        // Z partial stride (floats)
  const size_t TPS = (size_t)MP*BOT;
  const size_t HPS = (size_t)MP*(IMG+TXT);

  sort_kernel<<<1, 1024, 0, stream>>>(ids, rowmap, tileS);
  gather_voxels<<<MP, 256, 0, stream>>>(vox, rowmap, Vs);

  // K1: adapter down, NT=1: nx=1, KZ=8 (ksplit=512, nk=8) -> 8 partials
  gemm_bf16<EPI_SPLIT><<<MT*8, 256, 0, stream>>>(
      Vs, IN, ad_down_w, BOT, (long long)IN*BOT, tileS, rowmap, 1, 512,
      nullptr, 0, nullptr, 0, T1p, nullptr, BOT, TPS, nullptr);
  t1_epilogue<<<MP*BOT/256, 256, 0, stream>>>(T1p, ad_down_b, rowmap, tileS, T1);

  // K2: adapter up + residual, NT=32: nx=8, KZ=1 (nk=2) -> bf16 Hs
  gemm_bf16<EPI_RES_BF16><<<MT*32, 256, 0, stream>>>(
      T1, BOT, ad_up_w, IN, (long long)BOT*IN, tileS, rowmap, 8, 128,
      ad_up_b, IN, vox, IN, nullptr, Hs, IN, 0, nullptr);

  // K3: encoder, NT=16: nx=2, KZ=4 (ksplit=1024, nk=16) -> 4 partials, grid 704
  gemm_bf16<EPI_SPLIT><<<MT*16*4, 256, 0, stream>>>(
      Hs, IN, enc_w, H, (long long)IN*H, tileS, rowmap, 2, 1024,
      nullptr, 0, nullptr, 0, Zp, nullptr, H, ZPS, nullptr);
  ln_gelu_kernel<0,4><<<MP, 256, 0, stream>>>(Zp, ZPS, enc_ln_g, enc_ln_bb, H, enc_b,
                                              tileS, rowmap, Xf, Xb);

  // backbone: 6 x (NT=16: nx=4, KZ=2 (ksplit=1024, nk=16) -> 2 partials; grid 352)
  for (int d = 0; d < DEPTH; ++d){
    gemm_bf16<EPI_SPLIT><<<MT*16*2, 256, 0, stream>>>(
        Xb, H, bb_w + (size_t)d*H*H, H, 0, tileS, rowmap, 4, 1024,
        nullptr, 0, nullptr, 0, Zp, nullptr, H, ZPS, nullptr);
    ln_gelu_kernel<1,2><<<MP, 256, 0, stream>>>(Zp, ZPS, bb_ln_g + (size_t)d*H,
                                                bb_ln_b + (size_t)d*H, 0, bb_b + (size_t)d*H,
                                                tileS, rowmap, Xf, Xb);
  }

  // heads: ONE gemm (img cols 0..5, txt 6..11), NT=12: nx=4, KZ=2 (nk=16), grid 264
  gemm_bf16<EPI_HEADS><<<MT*12*2, 256, 0, stream>>>(
      Xb, H, img_w, IMG, 0, tileS, rowmap, 4, 1024,
      nullptr, 0, nullptr, 0, Hp, nullptr, IMG+TXT, HPS, txt_w);
  head_combine<<<MP, 384, 0, stream>>>(Hp, HPS, img_b, txt_b, rowmap,
                                       out, out + (size_t)BATCH*IMG);
}

// Round 11
// 495.995 us; speedup vs baseline: 1.1912x; 1.1912x over previous
//
#include <hip/hip_runtime.h>
#include <hip/hip_bf16.h>
#include <stdint.h>

typedef __bf16 bf16x8 __attribute__((ext_vector_type(8)));
typedef float  f32x4  __attribute__((ext_vector_type(4)));

#define DEV __device__ __forceinline__

constexpr int SUBJ  = 4;
constexpr int IN    = 4096;
constexpr int H     = 2048;
constexpr int DEPTH = 6;
constexpr int BATCH = 1024;
constexpr int BOT   = 128;
constexpr int IMG   = 768;
constexpr int TXT   = 768;
constexpr int MP    = 1408;   // padded sorted rows
constexpr int MT    = 11;     // MP/128 row tiles

DEV float gelu_exact(float x){ return 0.5f*x*(1.0f + erff(x*0.70710678118654752440f)); }

DEV uint32_t pk_bf16(float a, float b){
  __hip_bfloat16 ha = __float2bfloat16(a), hb = __float2bfloat16(b);
  return (uint32_t)*reinterpret_cast<uint16_t*>(&ha)
       | ((uint32_t)*reinterpret_cast<uint16_t*>(&hb) << 16);
}

// ---------------- subject counting-sort (1 block, 1024 threads) ----------------
__global__ void sort_kernel(const int* __restrict__ ids, int* __restrict__ rowmap,
                            int* __restrict__ tileS){
  __shared__ int hist[16][4];
  __shared__ int basew[16][4];
  __shared__ int pstart[5];
  int tid = threadIdx.x;
  if (tid < MP) rowmap[tid] = -1;
  if (tid + 1024 < MP) rowmap[tid + 1024] = -1;
  int w = tid >> 6, lane = tid & 63;
  int my = ids[tid];
  unsigned long long mymask = 0ull;
  #pragma unroll
  for (int s = 0; s < 4; ++s){
    unsigned long long m = __ballot(my == s);
    if (lane == 0) hist[w][s] = (int)__popcll(m);
    if (s == my) mymask = m;
  }
  int myrank = (int)__popcll(mymask & ((1ull << lane) - 1ull));
  __syncthreads();
  if (tid == 0){
    for (int s = 0; s < 4; ++s){
      int run = 0;
      for (int ww = 0; ww < 16; ++ww){ basew[ww][s] = run; run += hist[ww][s]; }
      hist[0][s] = run;
    }
    pstart[0] = 0;
    for (int s = 0; s < 4; ++s) pstart[s+1] = pstart[s] + ((hist[0][s] + 127) & ~127);
  }
  __syncthreads();
  int pos = pstart[my] + basew[w][my] + myrank;
  rowmap[pos] = tid;
  if (tid < MT){
    int row0 = tid << 7, s = -1;
    for (int ss = 0; ss < 4; ++ss) if (row0 >= pstart[ss] && row0 < pstart[ss+1]) s = ss;
    tileS[tid] = s;
  }
}

// ---------------- gather voxels into sorted order, fp32 -> bf16 ----------------
__global__ void gather_voxels(const float* __restrict__ vox, const int* __restrict__ rowmap,
                              __hip_bfloat16* __restrict__ Vs){
  int r = blockIdx.x, tid = threadIdx.x;
  int orig = rowmap[r];
  #pragma unroll
  for (int i = 0; i < 4; ++i){
    int c = (i*256 + tid) << 2;
    float4 v = {0.f,0.f,0.f,0.f};
    if (orig >= 0) v = *reinterpret_cast<const float4*>(vox + (size_t)orig*IN + c);
    __hip_bfloat16 o[4] = {__float2bfloat16(v.x), __float2bfloat16(v.y),
                           __float2bfloat16(v.z), __float2bfloat16(v.w)};
    *reinterpret_cast<uint2*>(Vs + (size_t)r*IN + c) = *reinterpret_cast<const uint2*>(o);
  }
}

// ---------------- 128x128 tile MFMA GEMM (R5 core), generalized split decode ----------
// Decode: xcd=b&7; r=b>>3; mt=r%MT; q=r/MT;
//         kzi = xcd/nx + (q/qnt)*(8/nx);  nt = (q%qnt)*nx + xcd%nx.
// kz correlated with XCD (L2 locality); split-K -> KZ partial buffers; no atomics.
// TAG distinguishes call sites in rocprof kernel names.
enum { EPI_SPLIT = 0, EPI_RES_BF16 = 1, EPI_HEADS = 3 };

template<int EPI, int TAG>
__global__ __launch_bounds__(256, 2)
void gemm_bf16(const __hip_bfloat16* __restrict__ A, int lda,
               const float* __restrict__ Bw, int ldn, long long wsub,
               const int* __restrict__ tileS, const int* __restrict__ rowmap,
               int nx, int qnt, int ksplit,
               const float* __restrict__ bias, int biassub,
               const float* __restrict__ resid, int ldres,
               float* __restrict__ outf, __hip_bfloat16* __restrict__ outb, int ldo,
               size_t pstride, const float* __restrict__ Bw2)
{
  int b   = blockIdx.x;
  int xcd = b & 7;
  int r0  = b >> 3;
  int mt  = r0 % MT;
  int q   = r0 / MT;
  int kzi = xcd / nx + (q / qnt) * (8 / nx);
  int nt  = (q % qnt) * nx + (xcd % nx);

  int s = tileS[mt];
  if (s < 0) return;                       // inactive (pad) row tile
  const __hip_bfloat16* Ab = A + (size_t)mt*128*lda;

  const float* Bb;
  int ntl = nt;
  if constexpr (EPI == EPI_HEADS){
    if (nt < 6){ Bb = Bw  + (size_t)nt*128; }
    else       { Bb = Bw2 + (size_t)(nt-6)*128; }
    ntl = nt;                              // col in concat [0,1536)
  } else {
    Bb = Bw + (size_t)s*wsub + (size_t)nt*128;
  }

  int kb = kzi * ksplit;
  int nk = ksplit >> 6;

  __shared__ __hip_bfloat16 sA[2][128*64];
  __shared__ __hip_bfloat16 sB[2][128*64];

  int tid = threadIdx.x;
  int lane = tid & 63;
  int wv = tid >> 6, wr = wv >> 1, wc = wv & 1;

  int kq = tid >> 5;
  int nq = tid & 31;
  int n4 = nq << 2;

  f32x4 acc[4][4];
  #pragma unroll
  for (int i = 0; i < 4; ++i)
    #pragma unroll
    for (int j = 0; j < 4; ++j) acc[i][j] = (f32x4){0.f,0.f,0.f,0.f};

  auto stageA = [&](int buf, int k0){
    #pragma unroll
    for (int i = 0; i < 4; ++i){
      int cell = i*256 + tid;
      int row = cell >> 3, cc = cell & 7;
      int kg = k0 + ((cc ^ (row & 7)) << 3);
      __builtin_amdgcn_global_load_lds(
        (const __attribute__((address_space(1))) void*)(Ab + (size_t)row*lda + kg),
        (__attribute__((address_space(3))) void*)(&sA[buf][cell<<3]), 16, 0, 0);
    }
  };

  auto stageB_load = [&](int k0g, float4* F){
    const float* p = Bb + (size_t)(k0g + (kq<<3))*ldn + n4;
    #pragma unroll
    for (int rr = 0; rr < 8; ++rr)
      F[rr] = *reinterpret_cast<const float4*>(p + (size_t)rr*ldn);
  };
  auto stageB_write = [&](int buf, const float4* F){
    #pragma unroll
    for (int j = 0; j < 4; ++j){
      int n = n4 + j;
      int cell = (kq ^ (n >> 3) ^ n) & 7;
      uint4 d;
      d.x = pk_bf16(((const float*)&F[0])[j], ((const float*)&F[1])[j]);
      d.y = pk_bf16(((const float*)&F[2])[j], ((const float*)&F[3])[j]);
      d.z = pk_bf16(((const float*)&F[4])[j], ((const float*)&F[5])[j]);
      d.w = pk_bf16(((const float*)&F[6])[j], ((const float*)&F[7])[j]);
      *reinterpret_cast<uint4*>(&sB[buf][(n<<6) + (cell<<3)]) = d;
    }
  };

  float4 F[8];
  stageB_load(kb, F);
  stageA(0, kb);
  stageB_write(0, F);
  __syncthreads();

  for (int t = 0; t < nk; ++t){
    if (t+1 < nk){
      stageB_load(kb + ((t+1)<<6), F);
      stageA((t+1)&1, kb + ((t+1)<<6));
    }
    const char* baseA = (const char*)(&sA[t&1][0]);
    const char* baseB = (const char*)(&sB[t&1][0]);
    int rA = (wr<<6) + (lane & 15);
    int rB = (wc<<6) + (lane & 15);
    #pragma unroll
    for (int kk = 0; kk < 2; ++kk){
      int koffA = ((((kk<<5) + ((lane>>4)<<3)) << 1)) ^ ((lane & 7) << 4);
      bf16x8 av[4], bv[4];
      #pragma unroll
      for (int f = 0; f < 4; ++f){
        int rowA = rA + f*16;
        av[f] = *reinterpret_cast<const bf16x8*>(baseA + (size_t)rowA*128 + koffA);
        int rowB = rB + f*16;
        int cellB = (((kk<<2) + (lane>>4)) ^ (rowB >> 3) ^ rowB) & 7;
        bv[f] = *reinterpret_cast<const bf16x8*>(baseB + (size_t)rowB*128 + (cellB<<4));
      }
      #pragma unroll
      for (int i = 0; i < 4; ++i)
        #pragma unroll
        for (int j = 0; j < 4; ++j)
          acc[i][j] = __builtin_amdgcn_mfma_f32_16x16x32_bf16(av[i], bv[j], acc[i][j], 0, 0, 0);
    }
    if (t+1 < nk) stageB_write((t+1)&1, F);
    __syncthreads();
  }

  // epilogue; C/D layout (m89-verified): col = lane&15, row = (lane>>4)*4 + reg
  #pragma unroll
  for (int i = 0; i < 4; ++i){
    int rbase = (mt<<7) + (wr<<6) + (i<<4) + ((lane>>4)<<2);
    #pragma unroll
    for (int j = 0; j < 4; ++j){
      int colp = (wc<<6) + (j<<4) + (lane & 15);
      #pragma unroll
      for (int qq = 0; qq < 4; ++qq){
        int r = rbase + qq;
        float v = acc[i][j][qq];
        if constexpr (EPI == EPI_SPLIT){
          int col = (nt<<7) + colp;
          outf[(size_t)kzi*pstride + (size_t)r*ldo + col] = v;
        } else if constexpr (EPI == EPI_RES_BF16){
          int col = (nt<<7) + colp;
          int orig = rowmap[r];
          if (orig >= 0){
            v += bias[(size_t)s*biassub + col] + resid[(size_t)orig*ldres + col];
            outb[(size_t)r*ldo + col] = __float2bfloat16(v);
          }
        } else { // EPI_HEADS: store to partial buffer (concat col space)
          int col = (ntl<<7) + colp;
          outf[(size_t)kzi*pstride + (size_t)r*ldo + col] = v;
        }
      }
    }
  }
}

// ---------------- T1 = gelu(sum_p T1p + db[s])  (bf16), 32 partials ----------------
__global__ void t1_epilogue(const float* __restrict__ Tp, const float* __restrict__ db,
                            const int* __restrict__ rowmap, const int* __restrict__ tileS,
                            __hip_bfloat16* __restrict__ T1){
  int idx = blockIdx.x*256 + threadIdx.x;
  int r = idx >> 7, c = idx & 127;
  float v = 0.f;
  if (rowmap[r] >= 0){
    int s = tileS[r >> 7];
    float acc = 0.f;
    #pragma unroll
    for (int p = 0; p < 32; ++p) acc += Tp[(size_t)p*MP*BOT + idx];
    v = gelu_exact(acc + db[s*BOT + c]);
  }
  T1[idx] = __float2bfloat16(v);
}

// ---------------- row LN over summed partials (+linear bias) + gelu (+residual) ------
template<int RES, int NPART>
__global__ void ln_gelu_kernel(const float* __restrict__ Zp, size_t pstride,
                               const float* __restrict__ g,
                               const float* __restrict__ b, int gsub,
                               const float* __restrict__ lb,
                               const int* __restrict__ tileS, const int* __restrict__ rowmap,
                               float* __restrict__ Xf, __hip_bfloat16* __restrict__ Xb){
  int r = blockIdx.x, tid = threadIdx.x;
  size_t rowoff = (size_t)r * H;
  int c0 = tid << 3;
  int orig = rowmap[r];
  if (orig < 0){
    float4 zf = {0.f,0.f,0.f,0.f};
    *reinterpret_cast<float4*>(Xf + rowoff + c0)     = zf;
    *reinterpret_cast<float4*>(Xf + rowoff + c0 + 4) = zf;
    uint4 zu = {0u,0u,0u,0u};
    *reinterpret_cast<uint4*>(Xb + rowoff + c0) = zu;
    return;
  }
  int si = gsub ? tileS[r>>7] : 0;
  const float* gp  = g  + (size_t)si*gsub;
  const float* bp  = b  + (size_t)si*gsub;
  const float* lbp = lb + (size_t)si*gsub;
  float z[8];
  #pragma unroll
  for (int j = 0; j < 8; ++j) z[j] = lbp[c0+j];
  #pragma unroll
  for (int p = 0; p < NPART; ++p){
    float4 v1 = *reinterpret_cast<const float4*>(Zp + p*pstride + rowoff + c0);
    float4 v2 = *reinterpret_cast<const float4*>(Zp + p*pstride + rowoff + c0 + 4);
    z[0]+=v1.x; z[1]+=v1.y; z[2]+=v1.z; z[3]+=v1.w;
    z[4]+=v2.x; z[5]+=v2.y; z[6]+=v2.z; z[7]+=v2.w;
  }
  float s1 = 0.f, s2 = 0.f;
  #pragma unroll
  for (int j = 0; j < 8; ++j){ s1 += z[j]; s2 += z[j]*z[j]; }
  #pragma unroll
  for (int m = 32; m >= 1; m >>= 1){ s1 += __shfl_xor(s1, m); s2 += __shfl_xor(s2, m); }
  __shared__ float red[4][2];
  int wv = tid >> 6, lane = tid & 63;
  if (lane == 0){ red[wv][0] = s1; red[wv][1] = s2; }
  __syncthreads();
  s1 = red[0][0]+red[1][0]+red[2][0]+red[3][0];
  s2 = red[0][1]+red[1][1]+red[2][1]+red[3][1];
  const float invH = 1.f / (float)H;
  float mu  = s1 * invH;
  float var = s2 * invH - mu*mu;
  float rs  = rsqrtf(var + 1e-5f);
  float o[8];
  #pragma unroll
  for (int j = 0; j < 8; ++j){
    float t = (z[j]-mu)*rs*gp[c0+j] + bp[c0+j];
    o[j] = gelu_exact(t);
  }
  if constexpr (RES){
    float4 x1 = *reinterpret_cast<const float4*>(Xf + rowoff + c0);
    float4 x2 = *reinterpret_cast<const float4*>(Xf + rowoff + c0 + 4);
    o[0]+=x1.x; o[1]+=x1.y; o[2]+=x1.z; o[3]+=x1.w;
    o[4]+=x2.x; o[5]+=x2.y; o[6]+=x2.z; o[7]+=x2.w;
  }
  float4 w1 = {o[0],o[1],o[2],o[3]}, w2 = {o[4],o[5],o[6],o[7]};
  *reinterpret_cast<float4*>(Xf + rowoff + c0)     = w1;
  *reinterpret_cast<float4*>(Xf + rowoff + c0 + 4) = w2;
  __hip_bfloat16 ob[8];
  #pragma unroll
  for (int j = 0; j < 8; ++j) ob[j] = __float2bfloat16(o[j]);
  *reinterpret_cast<uint4*>(Xb + rowoff + c0) = *reinterpret_cast<const uint4*>(ob);
}

// ---------------- heads combine: sum 2 partials + bias, scatter to original rows ------
__global__ void head_combine(const float* __restrict__ Hp, size_t pstride,
                             const float* __restrict__ img_b, const float* __restrict__ txt_b,
                             const int* __restrict__ rowmap,
                             float* __restrict__ oimg, float* __restrict__ otxt){
  int r = blockIdx.x;
  int orig = rowmap[r];
  if (orig < 0) return;
  int col = threadIdx.x << 2;                    // 384 threads x 4 cols = 1536
  size_t base = (size_t)r*(IMG+TXT) + col;
  float4 v0 = *reinterpret_cast<const float4*>(Hp + base);
  float4 v1 = *reinterpret_cast<const float4*>(Hp + pstride + base);
  float4 bb = (col < IMG)
            ? *reinterpret_cast<const float4*>(img_b + col)
            : *reinterpret_cast<const float4*>(txt_b + (col - IMG));
  float4 o = {v0.x+v1.x+bb.x, v0.y+v1.y+bb.y, v0.z+v1.z+bb.z, v0.w+v1.w+bb.w};
  if (col < IMG) *reinterpret_cast<float4*>(oimg + (size_t)orig*IMG + col) = o;
  else           *reinterpret_cast<float4*>(otxt + (size_t)orig*TXT + (col-IMG)) = o;
}

// ------------------------------------------------------------------------------
extern "C" void kernel_launch(void* const* d_in, const int* in_sizes, int n_in,
                              void* d_out, int out_size, void* d_ws, size_t ws_size,
                              hipStream_t stream){
  (void)in_sizes; (void)n_in; (void)out_size; (void)ws_size;
  const float* vox       = (const float*)d_in[0];
  const int*   ids       = (const int*)  d_in[1];
  const float* ad_down_w = (const float*)d_in[2];
  const float* ad_down_b = (const float*)d_in[3];
  const float* ad_up_w   = (const float*)d_in[4];
  const float* ad_up_b   = (const float*)d_in[5];
  const float* enc_w     = (const float*)d_in[6];
  const float* enc_b     = (const float*)d_in[7];
  const float* enc_ln_g  = (const float*)d_in[8];
  const float* enc_ln_bb = (const float*)d_in[9];
  const float* bb_w      = (const float*)d_in[10];
  const float* bb_b      = (const float*)d_in[11];
  const float* bb_ln_g   = (const float*)d_in[12];
  const float* bb_ln_b   = (const float*)d_in[13];
  const float* img_w     = (const float*)d_in[14];
  const float* img_b     = (const float*)d_in[15];
  const float* txt_w     = (const float*)d_in[16];
  const float* txt_b     = (const float*)d_in[17];
  float* out = (float*)d_out;

  char* wp = (char*)d_ws;
  auto alloc = [&](size_t bytes)->char*{ char* p = wp; wp += (bytes + 255) & ~(size_t)255; return p; };
  int* rowmap = (int*)alloc(MP * sizeof(int));
  int* tileS  = (int*)alloc(MT * sizeof(int));
  __hip_bfloat16* Vs    = (__hip_bfloat16*)alloc((size_t)MP*IN*2);
  float* T1p            = (float*)alloc((size_t)32*MP*BOT*4);
  __hip_bfloat16* T1    = (__hip_bfloat16*)alloc((size_t)MP*BOT*2);
  __hip_bfloat16* Hs    = (__hip_bfloat16*)alloc((size_t)MP*IN*2);
  float* Zp             = (float*)alloc((size_t)8*MP*H*4);
  float* Hp             = (float*)alloc((size_t)2*MP*(IMG+TXT)*4);
  float* Xf             = (float*)alloc((size_t)MP*H*4);
  __hip_bfloat16* Xb    = (__hip_bfloat16*)alloc((size_t)MP*H*2);

  const size_t ZPS = (size_t)MP*H;        // Z partial stride (floats)
  const size_t TPS = (size_t)MP*BOT;
  const size_t HPS = (size_t)MP*(IMG+TXT);

  sort_kernel<<<1, 1024, 0, stream>>>(ids, rowmap, tileS);
  gather_voxels<<<MP, 256, 0, stream>>>(vox, rowmap, Vs);

  // K1 (TAG 1): adapter down. NT=1, KZ=32 (nx=1, qnt=1, ksplit=128, nk=2), grid 352.
  gemm_bf16<EPI_SPLIT,1><<<MT*32, 256, 0, stream>>>(
      Vs, IN, ad_down_w, BOT, (long long)IN*BOT, tileS, rowmap, 1, 1, 128,
      nullptr, 0, nullptr, 0, T1p, nullptr, BOT, TPS, nullptr);
  t1_epilogue<<<MP*BOT/256, 256, 0, stream>>>(T1p, ad_down_b, rowmap, tileS, T1);

  // K2 (TAG 2): adapter up + residual. NT=32, KZ=1 (nx=8, qnt=4, ksplit=128), grid 352.
  gemm_bf16<EPI_RES_BF16,2><<<MT*32, 256, 0, stream>>>(
      T1, BOT, ad_up_w, IN, (long long)BOT*IN, tileS, rowmap, 8, 4, 128,
      ad_up_b, IN, vox, IN, nullptr, Hs, IN, 0, nullptr);

  // K3 (TAG 3): encoder. NT=16, KZ=8 (nx=1, qnt=16, ksplit=512, nk=8), grid 1408.
  gemm_bf16<EPI_SPLIT,3><<<MT*16*8, 256, 0, stream>>>(
      Hs, IN, enc_w, H, (long long)IN*H, tileS, rowmap, 1, 16, 512,
      nullptr, 0, nullptr, 0, Zp, nullptr, H, ZPS, nullptr);
  ln_gelu_kernel<0,8><<<MP, 256, 0, stream>>>(Zp, ZPS, enc_ln_g, enc_ln_bb, H, enc_b,
                                              tileS, rowmap, Xf, Xb);

  // backbone (TAG 4): R5-best config. NT=16, KZ=2 (nx=4, qnt=4, ksplit=1024), grid 352.
  for (int d = 0; d < DEPTH; ++d){
    gemm_bf16<EPI_SPLIT,4><<<MT*16*2, 256, 0, stream>>>(
        Xb, H, bb_w + (size_t)d*H*H, H, 0, tileS, rowmap, 4, 4, 1024,
        nullptr, 0, nullptr, 0, Zp, nullptr, H, ZPS, nullptr);
    ln_gelu_kernel<1,2><<<MP, 256, 0, stream>>>(Zp, ZPS, bb_ln_g + (size_t)d*H,
                                                bb_ln_b + (size_t)d*H, 0, bb_b + (size_t)d*H,
                                                tileS, rowmap, Xf, Xb);
  }

  // heads (TAG 5): NT=12, KZ=2 (nx=4, qnt=3, ksplit=1024), grid 264 -> 2 partials.
  gemm_bf16<EPI_HEADS,5><<<MT*12*2, 256, 0, stream>>>(
      Xb, H, img_w, IMG, 0, tileS, rowmap, 4, 3, 1024,
      nullptr, 0, nullptr, 0, Hp, nullptr, IMG+TXT, HPS, txt_w);
  head_combine<<<MP, 384, 0, stream>>>(Hp, HPS, img_b, txt_b, rowmap,
                                       out, out + (size_t)BATCH*IMG);
}

// Round 12
// 470.880 us; speedup vs baseline: 1.2547x; 1.0533x over previous
//
#include <hip/hip_runtime.h>
#include <hip/hip_bf16.h>
#include <stdint.h>

typedef __bf16 bf16x8 __attribute__((ext_vector_type(8)));
typedef float  f32x4  __attribute__((ext_vector_type(4)));

#define DEV __device__ __forceinline__

constexpr int SUBJ  = 4;
constexpr int IN    = 4096;
constexpr int H     = 2048;
constexpr int DEPTH = 6;
constexpr int BATCH = 1024;
constexpr int BOT   = 128;
constexpr int IMG   = 768;
constexpr int TXT   = 768;
constexpr int MP    = 1408;   // padded sorted rows
constexpr int MT    = 11;     // MP/128 row tiles

DEV float gelu_exact(float x){ return 0.5f*x*(1.0f + erff(x*0.70710678118654752440f)); }

DEV uint16_t bf16_bits(float x){
  __hip_bfloat16 h = __float2bfloat16(x);
  return *reinterpret_cast<uint16_t*>(&h);
}

// ---------------- one-shot fp32 -> bf16 weight conversion (same layout) ----------------
// 6 segments, contiguous in dst; pure streaming copy (read 264MB, write 132MB).
struct CvtSeg { const float* src; size_t dst_off; };
struct CvtParams { CvtSeg s[6]; size_t total_items; };

__global__ void convert_weights(CvtParams p, __hip_bfloat16* __restrict__ dst){
  size_t stride = (size_t)gridDim.x * blockDim.x;
  for (size_t it = (size_t)blockIdx.x*blockDim.x + threadIdx.x; it < p.total_items; it += stride){
    size_t e = it << 3;                       // 8 elements per item
    int si = 0;
    #pragma unroll
    for (int i = 1; i < 6; ++i) if (e >= p.s[i].dst_off) si = i;
    const float* s = p.s[si].src + (e - p.s[si].dst_off);
    float4 a = *reinterpret_cast<const float4*>(s);
    float4 b = *reinterpret_cast<const float4*>(s + 4);
    uint16_t o[8] = {bf16_bits(a.x), bf16_bits(a.y), bf16_bits(a.z), bf16_bits(a.w),
                     bf16_bits(b.x), bf16_bits(b.y), bf16_bits(b.z), bf16_bits(b.w)};
    *reinterpret_cast<uint4*>(dst + e) = *reinterpret_cast<const uint4*>(o);
  }
}

// ---------------- subject counting-sort (1 block, 1024 threads) ----------------
__global__ void sort_kernel(const int* __restrict__ ids, int* __restrict__ rowmap,
                            int* __restrict__ tileS){
  __shared__ int hist[16][4];
  __shared__ int basew[16][4];
  __shared__ int pstart[5];
  int tid = threadIdx.x;
  if (tid < MP) rowmap[tid] = -1;
  if (tid + 1024 < MP) rowmap[tid + 1024] = -1;
  int w = tid >> 6, lane = tid & 63;
  int my = ids[tid];
  unsigned long long mymask = 0ull;
  #pragma unroll
  for (int s = 0; s < 4; ++s){
    unsigned long long m = __ballot(my == s);
    if (lane == 0) hist[w][s] = (int)__popcll(m);
    if (s == my) mymask = m;
  }
  int myrank = (int)__popcll(mymask & ((1ull << lane) - 1ull));
  __syncthreads();
  if (tid == 0){
    for (int s = 0; s < 4; ++s){
      int run = 0;
      for (int ww = 0; ww < 16; ++ww){ basew[ww][s] = run; run += hist[ww][s]; }
      hist[0][s] = run;
    }
    pstart[0] = 0;
    for (int s = 0; s < 4; ++s) pstart[s+1] = pstart[s] + ((hist[0][s] + 127) & ~127);
  }
  __syncthreads();
  int pos = pstart[my] + basew[w][my] + myrank;
  rowmap[pos] = tid;
  if (tid < MT){
    int row0 = tid << 7, s = -1;
    for (int ss = 0; ss < 4; ++ss) if (row0 >= pstart[ss] && row0 < pstart[ss+1]) s = ss;
    tileS[tid] = s;
  }
}

// ---------------- gather voxels into sorted order, fp32 -> bf16 ----------------
__global__ void gather_voxels(const float* __restrict__ vox, const int* __restrict__ rowmap,
                              __hip_bfloat16* __restrict__ Vs){
  int r = blockIdx.x, tid = threadIdx.x;
  int orig = rowmap[r];
  #pragma unroll
  for (int i = 0; i < 4; ++i){
    int c = (i*256 + tid) << 2;
    float4 v = {0.f,0.f,0.f,0.f};
    if (orig >= 0) v = *reinterpret_cast<const float4*>(vox + (size_t)orig*IN + c);
    __hip_bfloat16 o[4] = {__float2bfloat16(v.x), __float2bfloat16(v.y),
                           __float2bfloat16(v.z), __float2bfloat16(v.w)};
    *reinterpret_cast<uint2*>(Vs + (size_t)r*IN + c) = *reinterpret_cast<const uint2*>(o);
  }
}

// ---------------- 128x128 tile MFMA GEMM, bf16 B [K][N] (pre-converted) --------------
// Decode: xcd=b&7; r=b>>3; mt=r%MT; q=r/MT;
//         kzi = xcd/nx + (q/qnt)*(8/nx);  nt = (q%qnt)*nx + xcd%nx.
// kz correlated with XCD (L2 locality); split-K -> KZ partial buffers; no atomics.
enum { EPI_SPLIT = 0, EPI_RES_BF16 = 1, EPI_HEADS = 3 };

template<int EPI, int TAG>
__global__ __launch_bounds__(256, 2)
void gemm_bf16(const __hip_bfloat16* __restrict__ A, int lda,
               const __hip_bfloat16* __restrict__ Bw, int ldn, long long wsub,
               const int* __restrict__ tileS, const int* __restrict__ rowmap,
               int nx, int qnt, int ksplit,
               const float* __restrict__ bias, int biassub,
               const float* __restrict__ resid, int ldres,
               float* __restrict__ outf, __hip_bfloat16* __restrict__ outb, int ldo,
               size_t pstride, const __hip_bfloat16* __restrict__ Bw2)
{
  int b   = blockIdx.x;
  int xcd = b & 7;
  int r0  = b >> 3;
  int mt  = r0 % MT;
  int q   = r0 / MT;
  int kzi = xcd / nx + (q / qnt) * (8 / nx);
  int nt  = (q % qnt) * nx + (xcd % nx);

  int s = tileS[mt];
  if (s < 0) return;                       // inactive (pad) row tile
  const __hip_bfloat16* Ab = A + (size_t)mt*128*lda;

  const __hip_bfloat16* Bb;
  int ntl = nt;
  if constexpr (EPI == EPI_HEADS){
    if (nt < 6){ Bb = Bw  + (size_t)nt*128; }
    else       { Bb = Bw2 + (size_t)(nt-6)*128; }
    ntl = nt;                              // col in concat [0,1536)
  } else {
    Bb = Bw + (size_t)s*wsub + (size_t)nt*128;
  }

  int kb = kzi * ksplit;
  int nk = ksplit >> 6;

  __shared__ __hip_bfloat16 sA[2][128*64];
  __shared__ __hip_bfloat16 sB[2][128*64];

  int tid = threadIdx.x;
  int lane = tid & 63;
  int wv = tid >> 6, wr = wv >> 1, wc = wv & 1;

  int kq = tid >> 5;                       // 0..7: k-chunk of 8 rows
  int nq = tid & 31;                       // n-col group of 4
  int n4 = nq << 2;

  f32x4 acc[4][4];
  #pragma unroll
  for (int i = 0; i < 4; ++i)
    #pragma unroll
    for (int j = 0; j < 4; ++j) acc[i][j] = (f32x4){0.f,0.f,0.f,0.f};

  auto stageA = [&](int buf, int k0){
    #pragma unroll
    for (int i = 0; i < 4; ++i){
      int cell = i*256 + tid;
      int row = cell >> 3, cc = cell & 7;
      int kg = k0 + ((cc ^ (row & 7)) << 3);
      __builtin_amdgcn_global_load_lds(
        (const __attribute__((address_space(1))) void*)(Ab + (size_t)row*lda + kg),
        (__attribute__((address_space(3))) void*)(&sA[buf][cell<<3]), 16, 0, 0);
    }
  };

  // B bf16 [K][N]: 8 rows x 4 cols per thread, uint2 (8B) per row
  auto stageB_load = [&](int k0g, uint2* F){
    const __hip_bfloat16* p = Bb + (size_t)(k0g + (kq<<3))*ldn + n4;
    #pragma unroll
    for (int rr = 0; rr < 8; ++rr)
      F[rr] = *reinterpret_cast<const uint2*>(p + (size_t)rr*ldn);
  };
  auto stageB_write = [&](int buf, const uint2* F){
    #pragma unroll
    for (int j = 0; j < 4; ++j){
      int n = n4 + j;
      int cell = (kq ^ (n >> 3) ^ n) & 7;
      auto US = [&](int rr)->uint32_t{
        return (((const uint32_t*)&F[rr])[j >> 1] >> ((j & 1) * 16)) & 0xffffu;
      };
      uint4 d;
      d.x = US(0) | (US(1) << 16);
      d.y = US(2) | (US(3) << 16);
      d.z = US(4) | (US(5) << 16);
      d.w = US(6) | (US(7) << 16);
      *reinterpret_cast<uint4*>(&sB[buf][(n<<6) + (cell<<3)]) = d;
    }
  };

  uint2 F[8];
  stageB_load(kb, F);
  stageA(0, kb);
  stageB_write(0, F);
  __syncthreads();

  for (int t = 0; t < nk; ++t){
    if (t+1 < nk){
      stageB_load(kb + ((t+1)<<6), F);
      stageA((t+1)&1, kb + ((t+1)<<6));
    }
    const char* baseA = (const char*)(&sA[t&1][0]);
    const char* baseB = (const char*)(&sB[t&1][0]);
    int rA = (wr<<6) + (lane & 15);
    int rB = (wc<<6) + (lane & 15);
    #pragma unroll
    for (int kk = 0; kk < 2; ++kk){
      int koffA = ((((kk<<5) + ((lane>>4)<<3)) << 1)) ^ ((lane & 7) << 4);
      bf16x8 av[4], bv[4];
      #pragma unroll
      for (int f = 0; f < 4; ++f){
        int rowA = rA + f*16;
        av[f] = *reinterpret_cast<const bf16x8*>(baseA + (size_t)rowA*128 + koffA);
        int rowB = rB + f*16;
        int cellB = (((kk<<2) + (lane>>4)) ^ (rowB >> 3) ^ rowB) & 7;
        bv[f] = *reinterpret_cast<const bf16x8*>(baseB + (size_t)rowB*128 + (cellB<<4));
      }
      #pragma unroll
      for (int i = 0; i < 4; ++i)
        #pragma unroll
        for (int j = 0; j < 4; ++j)
          acc[i][j] = __builtin_amdgcn_mfma_f32_16x16x32_bf16(av[i], bv[j], acc[i][j], 0, 0, 0);
    }
    if (t+1 < nk) stageB_write((t+1)&1, F);
    __syncthreads();
  }

  // epilogue; C/D layout (m89-verified): col = lane&15, row = (lane>>4)*4 + reg
  #pragma unroll
  for (int i = 0; i < 4; ++i){
    int rbase = (mt<<7) + (wr<<6) + (i<<4) + ((lane>>4)<<2);
    #pragma unroll
    for (int j = 0; j < 4; ++j){
      int colp = (wc<<6) + (j<<4) + (lane & 15);
      #pragma unroll
      for (int qq = 0; qq < 4; ++qq){
        int r = rbase + qq;
        float v = acc[i][j][qq];
        if constexpr (EPI == EPI_SPLIT){
          int col = (nt<<7) + colp;
          outf[(size_t)kzi*pstride + (size_t)r*ldo + col] = v;
        } else if constexpr (EPI == EPI_RES_BF16){
          int col = (nt<<7) + colp;
          int orig = rowmap[r];
          if (orig >= 0){
            v += bias[(size_t)s*biassub + col] + resid[(size_t)orig*ldres + col];
            outb[(size_t)r*ldo + col] = __float2bfloat16(v);
          }
        } else { // EPI_HEADS: store to partial buffer (concat col space)
          int col = (ntl<<7) + colp;
          outf[(size_t)kzi*pstride + (size_t)r*ldo + col] = v;
        }
      }
    }
  }
}

// ---------------- T1 = gelu(sum_p T1p + db[s])  (bf16) ----------------
template<int NPART>
__global__ void t1_epilogue(const float* __restrict__ Tp, const float* __restrict__ db,
                            const int* __restrict__ rowmap, const int* __restrict__ tileS,
                            __hip_bfloat16* __restrict__ T1){
  int idx = blockIdx.x*256 + threadIdx.x;
  int r = idx >> 7, c = idx & 127;
  float v = 0.f;
  if (rowmap[r] >= 0){
    int s = tileS[r >> 7];
    float acc = 0.f;
    #pragma unroll
    for (int p = 0; p < NPART; ++p) acc += Tp[(size_t)p*MP*BOT + idx];
    v = gelu_exact(acc + db[s*BOT + c]);
  }
  T1[idx] = __float2bfloat16(v);
}

// ---------------- row LN over summed partials (+linear bias) + gelu (+residual) ------
template<int RES, int NPART>
__global__ void ln_gelu_kernel(const float* __restrict__ Zp, size_t pstride,
                               const float* __restrict__ g,
                               const float* __restrict__ b, int gsub,
                               const float* __restrict__ lb,
                               const int* __restrict__ tileS, const int* __restrict__ rowmap,
                               float* __restrict__ Xf, __hip_bfloat16* __restrict__ Xb){
  int r = blockIdx.x, tid = threadIdx.x;
  size_t rowoff = (size_t)r * H;
  int c0 = tid << 3;
  int orig = rowmap[r];
  if (orig < 0){
    float4 zf = {0.f,0.f,0.f,0.f};
    *reinterpret_cast<float4*>(Xf + rowoff + c0)     = zf;
    *reinterpret_cast<float4*>(Xf + rowoff + c0 + 4) = zf;
    uint4 zu = {0u,0u,0u,0u};
    *reinterpret_cast<uint4*>(Xb + rowoff + c0) = zu;
    return;
  }
  int si = gsub ? tileS[r>>7] : 0;
  const float* gp  = g  + (size_t)si*gsub;
  const float* bp  = b  + (size_t)si*gsub;
  const float* lbp = lb + (size_t)si*gsub;
  float z[8];
  #pragma unroll
  for (int j = 0; j < 8; ++j) z[j] = lbp[c0+j];
  #pragma unroll
  for (int p = 0; p < NPART; ++p){
    float4 v1 = *reinterpret_cast<const float4*>(Zp + p*pstride + rowoff + c0);
    float4 v2 = *reinterpret_cast<const float4*>(Zp + p*pstride + rowoff + c0 + 4);
    z[0]+=v1.x; z[1]+=v1.y; z[2]+=v1.z; z[3]+=v1.w;
    z[4]+=v2.x; z[5]+=v2.y; z[6]+=v2.z; z[7]+=v2.w;
  }
  float s1 = 0.f, s2 = 0.f;
  #pragma unroll
  for (int j = 0; j < 8; ++j){ s1 += z[j]; s2 += z[j]*z[j]; }
  #pragma unroll
  for (int m = 32; m >= 1; m >>= 1){ s1 += __shfl_xor(s1, m); s2 += __shfl_xor(s2, m); }
  __shared__ float red[4][2];
  int wv = tid >> 6, lane = tid & 63;
  if (lane == 0){ red[wv][0] = s1; red[wv][1] = s2; }
  __syncthreads();
  s1 = red[0][0]+red[1][0]+red[2][0]+red[3][0];
  s2 = red[0][1]+red[1][1]+red[2][1]+red[3][1];
  const float invH = 1.f / (float)H;
  float mu  = s1 * invH;
  float var = s2 * invH - mu*mu;
  float rs  = rsqrtf(var + 1e-5f);
  float o[8];
  #pragma unroll
  for (int j = 0; j < 8; ++j){
    float t = (z[j]-mu)*rs*gp[c0+j] + bp[c0+j];
    o[j] = gelu_exact(t);
  }
  if constexpr (RES){
    float4 x1 = *reinterpret_cast<const float4*>(Xf + rowoff + c0);
    float4 x2 = *reinterpret_cast<const float4*>(Xf + rowoff + c0 + 4);
    o[0]+=x1.x; o[1]+=x1.y; o[2]+=x1.z; o[3]+=x1.w;
    o[4]+=x2.x; o[5]+=x2.y; o[6]+=x2.z; o[7]+=x2.w;
  }
  float4 w1 = {o[0],o[1],o[2],o[3]}, w2 = {o[4],o[5],o[6],o[7]};
  *reinterpret_cast<float4*>(Xf + rowoff + c0)     = w1;
  *reinterpret_cast<float4*>(Xf + rowoff + c0 + 4) = w2;
  __hip_bfloat16 ob[8];
  #pragma unroll
  for (int j = 0; j < 8; ++j) ob[j] = __float2bfloat16(o[j]);
  *reinterpret_cast<uint4*>(Xb + rowoff + c0) = *reinterpret_cast<const uint4*>(ob);
}

// ---------------- heads combine: sum 2 partials + bias, scatter to original rows ------
__global__ void head_combine(const float* __restrict__ Hp, size_t pstride,
                             const float* __restrict__ img_b, const float* __restrict__ txt_b,
                             const int* __restrict__ rowmap,
                             float* __restrict__ oimg, float* __restrict__ otxt){
  int r = blockIdx.x;
  int orig = rowmap[r];
  if (orig < 0) return;
  int col = threadIdx.x << 2;                    // 384 threads x 4 cols = 1536
  size_t base = (size_t)r*(IMG+TXT) + col;
  float4 v0 = *reinterpret_cast<const float4*>(Hp + base);
  float4 v1 = *reinterpret_cast<const float4*>(Hp + pstride + base);
  float4 bb = (col < IMG)
            ? *reinterpret_cast<const float4*>(img_b + col)
            : *reinterpret_cast<const float4*>(txt_b + (col - IMG));
  float4 o = {v0.x+v1.x+bb.x, v0.y+v1.y+bb.y, v0.z+v1.z+bb.z, v0.w+v1.w+bb.w};
  if (col < IMG) *reinterpret_cast<float4*>(oimg + (size_t)orig*IMG + col) = o;
  else           *reinterpret_cast<float4*>(otxt + (size_t)orig*TXT + (col-IMG)) = o;
}

// ------------------------------------------------------------------------------
extern "C" void kernel_launch(void* const* d_in, const int* in_sizes, int n_in,
                              void* d_out, int out_size, void* d_ws, size_t ws_size,
                              hipStream_t stream){
  (void)in_sizes; (void)n_in; (void)out_size; (void)ws_size;
  const float* vox       = (const float*)d_in[0];
  const int*   ids       = (const int*)  d_in[1];
  const float* ad_down_w = (const float*)d_in[2];
  const float* ad_down_b = (const float*)d_in[3];
  const float* ad_up_w   = (const float*)d_in[4];
  const float* ad_up_b   = (const float*)d_in[5];
  const float* enc_w     = (const float*)d_in[6];
  const float* enc_b     = (const float*)d_in[7];
  const float* enc_ln_g  = (const float*)d_in[8];
  const float* enc_ln_bb = (const float*)d_in[9];
  const float* bb_w      = (const float*)d_in[10];
  const float* bb_b      = (const float*)d_in[11];
  const float* bb_ln_g   = (const float*)d_in[12];
  const float* bb_ln_b   = (const float*)d_in[13];
  const float* img_w     = (const float*)d_in[14];
  const float* img_b     = (const float*)d_in[15];
  const float* txt_w     = (const float*)d_in[16];
  const float* txt_b     = (const float*)d_in[17];
  float* out = (float*)d_out;

  // bf16 weight pool segment sizes (elements)
  const size_t N_DOWN = (size_t)SUBJ*IN*BOT;     // 2,097,152
  const size_t N_UP   = (size_t)SUBJ*BOT*IN;     // 2,097,152
  const size_t N_ENC  = (size_t)SUBJ*IN*H;       // 33,554,432
  const size_t N_BB   = (size_t)DEPTH*H*H;       // 25,165,824
  const size_t N_IMG  = (size_t)H*IMG;           // 1,572,864
  const size_t N_TXT  = (size_t)H*TXT;           // 1,572,864

  char* wp = (char*)d_ws;
  auto alloc = [&](size_t bytes)->char*{ char* p = wp; wp += (bytes + 255) & ~(size_t)255; return p; };
  int* rowmap = (int*)alloc(MP * sizeof(int));
  int* tileS  = (int*)alloc(MT * sizeof(int));
  __hip_bfloat16* Wbf = (__hip_bfloat16*)alloc((N_DOWN+N_UP+N_ENC+N_BB+N_IMG+N_TXT)*2);
  __hip_bfloat16* w_down = Wbf;
  __hip_bfloat16* w_up   = w_down + N_DOWN;
  __hip_bfloat16* w_enc  = w_up   + N_UP;
  __hip_bfloat16* w_bb   = w_enc  + N_ENC;
  __hip_bfloat16* w_img  = w_bb   + N_BB;
  __hip_bfloat16* w_txt  = w_img  + N_IMG;
  __hip_bfloat16* Vs    = (__hip_bfloat16*)alloc((size_t)MP*IN*2);
  float* T1p            = (float*)alloc((size_t)16*MP*BOT*4);
  __hip_bfloat16* T1    = (__hip_bfloat16*)alloc((size_t)MP*BOT*2);
  __hip_bfloat16* Hs    = (__hip_bfloat16*)alloc((size_t)MP*IN*2);
  float* Zp             = (float*)alloc((size_t)4*MP*H*4);
  float* Hp             = Zp;               // alias: Zp dead before heads GEMM writes Hp
  float* Xf             = (float*)alloc((size_t)MP*H*4);
  __hip_bfloat16* Xb    = (__hip_bfloat16*)alloc((size_t)MP*H*2);

  const size_t ZPS = (size_t)MP*H;
  const size_t TPS = (size_t)MP*BOT;
  const size_t HPS = (size_t)MP*(IMG+TXT);

  // weight conversion pass (runs first; pure streaming 264MB->132MB)
  CvtParams cp;
  size_t off = 0;
  cp.s[0] = {ad_down_w, off}; off += N_DOWN;
  cp.s[1] = {ad_up_w,   off}; off += N_UP;
  cp.s[2] = {enc_w,     off}; off += N_ENC;
  cp.s[3] = {bb_w,      off}; off += N_BB;
  cp.s[4] = {img_w,     off}; off += N_IMG;
  cp.s[5] = {txt_w,     off}; off += N_TXT;
  cp.total_items = off >> 3;
  convert_weights<<<2048, 256, 0, stream>>>(cp, Wbf);

  sort_kernel<<<1, 1024, 0, stream>>>(ids, rowmap, tileS);
  gather_voxels<<<MP, 256, 0, stream>>>(vox, rowmap, Vs);

  // K1: adapter down. NT=1, KZ=16 (nx=1, qnt=1, ksplit=256, nk=4), grid 176.
  gemm_bf16<EPI_SPLIT,1><<<MT*16, 256, 0, stream>>>(
      Vs, IN, w_down, BOT, (long long)IN*BOT, tileS, rowmap, 1, 1, 256,
      nullptr, 0, nullptr, 0, T1p, nullptr, BOT, TPS, nullptr);
  t1_epilogue<16><<<MP*BOT/256, 256, 0, stream>>>(T1p, ad_down_b, rowmap, tileS, T1);

  // K2: adapter up + residual. NT=32, KZ=1 (nx=8, qnt=4, ksplit=128), grid 352.
  gemm_bf16<EPI_RES_BF16,2><<<MT*32, 256, 0, stream>>>(
      T1, BOT, w_up, IN, (long long)BOT*IN, tileS, rowmap, 8, 4, 128,
      ad_up_b, IN, vox, IN, nullptr, Hs, IN, 0, nullptr);

  // K3: encoder. NT=16, KZ=4 (nx=2, qnt=8, ksplit=1024, nk=16), grid 704.
  gemm_bf16<EPI_SPLIT,3><<<MT*8*8, 256, 0, stream>>>(
      Hs, IN, w_enc, H, (long long)IN*H, tileS, rowmap, 2, 8, 1024,
      nullptr, 0, nullptr, 0, Zp, nullptr, H, ZPS, nullptr);
  ln_gelu_kernel<0,4><<<MP, 256, 0, stream>>>(Zp, ZPS, enc_ln_g, enc_ln_bb, H, enc_b,
                                              tileS, rowmap, Xf, Xb);

  // backbone: 6 x (NT=16, KZ=2 (nx=4, qnt=4, ksplit=1024), grid 352; WS/XCD ~3.9MB)
  for (int d = 0; d < DEPTH; ++d){
    gemm_bf16<EPI_SPLIT,4><<<MT*4*8, 256, 0, stream>>>(
        Xb, H, w_bb + (size_t)d*H*H, H, 0, tileS, rowmap, 4, 4, 1024,
        nullptr, 0, nullptr, 0, Zp, nullptr, H, ZPS, nullptr);
    ln_gelu_kernel<1,2><<<MP, 256, 0, stream>>>(Zp, ZPS, bb_ln_g + (size_t)d*H,
                                                bb_ln_b + (size_t)d*H, 0, bb_b + (size_t)d*H,
                                                tileS, rowmap, Xf, Xb);
  }

  // heads: ONE gemm (img cols 0..5, txt 6..11), NT=12, KZ=2 (nx=4, qnt=3), grid 264.
  gemm_bf16<EPI_HEADS,5><<<MT*3*8, 256, 0, stream>>>(
      Xb, H, w_img, IMG, 0, tileS, rowmap, 4, 3, 1024,
      nullptr, 0, nullptr, 0, Hp, nullptr, IMG+TXT, HPS, w_txt);
  head_combine<<<MP, 384, 0, stream>>>(Hp, HPS, img_b, txt_b, rowmap,
                                       out, out + (size_t)BATCH*IMG);
}

// Round 13
// 469.100 us; speedup vs baseline: 1.2594x; 1.0038x over previous
//
#include <hip/hip_runtime.h>
#include <hip/hip_bf16.h>
#include <stdint.h>

typedef __bf16 bf16x8 __attribute__((ext_vector_type(8)));
typedef float  f32x4  __attribute__((ext_vector_type(4)));
typedef float  vf4    __attribute__((ext_vector_type(4)));
typedef unsigned int vu4 __attribute__((ext_vector_type(4)));

#define DEV __device__ __forceinline__

constexpr int SUBJ  = 4;
constexpr int IN    = 4096;
constexpr int H     = 2048;
constexpr int DEPTH = 6;
constexpr int BATCH = 1024;
constexpr int BOT   = 128;
constexpr int IMG   = 768;
constexpr int TXT   = 768;
constexpr int MP    = 1408;   // padded sorted rows
constexpr int MT    = 11;     // MP/128 row tiles

DEV float gelu_exact(float x){ return 0.5f*x*(1.0f + erff(x*0.70710678118654752440f)); }

DEV uint16_t bf16_bits(float x){
  __hip_bfloat16 h = __float2bfloat16(x);
  return *reinterpret_cast<uint16_t*>(&h);
}

// ---------------- one-shot fp32 -> bf16 weight conversion (same layout) ----------------
// One 16-element chunk per thread (no loop): 4 independent NT float4 loads + 2 stores.
// NT loads: the fp32 source is DEAD after this kernel -> never allocate it in L2/L3.
// Normal stores: the bf16 pool is re-read by every GEMM -> let it cache in L3.
struct CvtSeg { const float* src; size_t dst_off; };
struct CvtParams { CvtSeg s[6]; size_t total_items; };

__global__ void convert_weights(CvtParams p, __hip_bfloat16* __restrict__ dst){
  size_t it = (size_t)blockIdx.x*blockDim.x + threadIdx.x;
  if (it >= p.total_items) return;
  size_t e = it << 4;                       // 16 elements per thread
  int si = 0;
  #pragma unroll
  for (int i = 1; i < 6; ++i) if (e >= p.s[i].dst_off) si = i;
  const float* s = p.s[si].src + (e - p.s[si].dst_off);
  vf4 a = __builtin_nontemporal_load(reinterpret_cast<const vf4*>(s));
  vf4 b = __builtin_nontemporal_load(reinterpret_cast<const vf4*>(s + 4));
  vf4 c = __builtin_nontemporal_load(reinterpret_cast<const vf4*>(s + 8));
  vf4 d = __builtin_nontemporal_load(reinterpret_cast<const vf4*>(s + 12));
  uint16_t o[16] = {bf16_bits(a.x), bf16_bits(a.y), bf16_bits(a.z), bf16_bits(a.w),
                    bf16_bits(b.x), bf16_bits(b.y), bf16_bits(b.z), bf16_bits(b.w),
                    bf16_bits(c.x), bf16_bits(c.y), bf16_bits(c.z), bf16_bits(c.w),
                    bf16_bits(d.x), bf16_bits(d.y), bf16_bits(d.z), bf16_bits(d.w)};
  *reinterpret_cast<uint4*>(dst + e)     = *reinterpret_cast<const uint4*>(&o[0]);
  *reinterpret_cast<uint4*>(dst + e + 8) = *reinterpret_cast<const uint4*>(&o[8]);
}

// ---------------- subject counting-sort (1 block, 1024 threads) ----------------
__global__ void sort_kernel(const int* __restrict__ ids, int* __restrict__ rowmap,
                            int* __restrict__ tileS){
  __shared__ int hist[16][4];
  __shared__ int basew[16][4];
  __shared__ int pstart[5];
  int tid = threadIdx.x;
  if (tid < MP) rowmap[tid] = -1;
  if (tid + 1024 < MP) rowmap[tid + 1024] = -1;
  int w = tid >> 6, lane = tid & 63;
  int my = ids[tid];
  unsigned long long mymask = 0ull;
  #pragma unroll
  for (int s = 0; s < 4; ++s){
    unsigned long long m = __ballot(my == s);
    if (lane == 0) hist[w][s] = (int)__popcll(m);
    if (s == my) mymask = m;
  }
  int myrank = (int)__popcll(mymask & ((1ull << lane) - 1ull));
  __syncthreads();
  if (tid == 0){
    for (int s = 0; s < 4; ++s){
      int run = 0;
      for (int ww = 0; ww < 16; ++ww){ basew[ww][s] = run; run += hist[ww][s]; }
      hist[0][s] = run;
    }
    pstart[0] = 0;
    for (int s = 0; s < 4; ++s) pstart[s+1] = pstart[s] + ((hist[0][s] + 127) & ~127);
  }
  __syncthreads();
  int pos = pstart[my] + basew[w][my] + myrank;
  rowmap[pos] = tid;
  if (tid < MT){
    int row0 = tid << 7, s = -1;
    for (int ss = 0; ss < 4; ++ss) if (row0 >= pstart[ss] && row0 < pstart[ss+1]) s = ss;
    tileS[tid] = s;
  }
}

// ---------------- gather voxels into sorted order, fp32 -> bf16 ----------------
__global__ void gather_voxels(const float* __restrict__ vox, const int* __restrict__ rowmap,
                              __hip_bfloat16* __restrict__ Vs){
  int r = blockIdx.x, tid = threadIdx.x;
  int orig = rowmap[r];
  #pragma unroll
  for (int i = 0; i < 4; ++i){
    int c = (i*256 + tid) << 2;
    float4 v = {0.f,0.f,0.f,0.f};
    if (orig >= 0) v = *reinterpret_cast<const float4*>(vox + (size_t)orig*IN + c);
    __hip_bfloat16 o[4] = {__float2bfloat16(v.x), __float2bfloat16(v.y),
                           __float2bfloat16(v.z), __float2bfloat16(v.w)};
    *reinterpret_cast<uint2*>(Vs + (size_t)r*IN + c) = *reinterpret_cast<const uint2*>(o);
  }
}

// ---------------- 128x128 tile MFMA GEMM, bf16 B [K][N] (pre-converted) --------------
// Decode: xcd=b&7; r=b>>3; mt=r%MT; q=r/MT;
//         kzi = xcd/nx + (q/qnt)*(8/nx);  nt = (q%qnt)*nx + xcd%nx.
// kz correlated with XCD (L2 locality); split-K -> KZ partial buffers; no atomics.
enum { EPI_SPLIT = 0, EPI_RES_BF16 = 1, EPI_HEADS = 3 };

template<int EPI, int TAG>
__global__ __launch_bounds__(256, 2)
void gemm_bf16(const __hip_bfloat16* __restrict__ A, int lda,
               const __hip_bfloat16* __restrict__ Bw, int ldn, long long wsub,
               const int* __restrict__ tileS, const int* __restrict__ rowmap,
               int nx, int qnt, int ksplit,
               const float* __restrict__ bias, int biassub,
               const float* __restrict__ resid, int ldres,
               float* __restrict__ outf, __hip_bfloat16* __restrict__ outb, int ldo,
               size_t pstride, const __hip_bfloat16* __restrict__ Bw2)
{
  int b   = blockIdx.x;
  int xcd = b & 7;
  int r0  = b >> 3;
  int mt  = r0 % MT;
  int q   = r0 / MT;
  int kzi = xcd / nx + (q / qnt) * (8 / nx);
  int nt  = (q % qnt) * nx + (xcd % nx);

  int s = tileS[mt];
  if (s < 0) return;                       // inactive (pad) row tile
  const __hip_bfloat16* Ab = A + (size_t)mt*128*lda;

  const __hip_bfloat16* Bb;
  int ntl = nt;
  if constexpr (EPI == EPI_HEADS){
    if (nt < 6){ Bb = Bw  + (size_t)nt*128; }
    else       { Bb = Bw2 + (size_t)(nt-6)*128; }
    ntl = nt;                              // col in concat [0,1536)
  } else {
    Bb = Bw + (size_t)s*wsub + (size_t)nt*128;
  }

  int kb = kzi * ksplit;
  int nk = ksplit >> 6;

  __shared__ __hip_bfloat16 sA[2][128*64];
  __shared__ __hip_bfloat16 sB[2][128*64];

  int tid = threadIdx.x;
  int lane = tid & 63;
  int wv = tid >> 6, wr = wv >> 1, wc = wv & 1;

  int kq = tid >> 5;                       // 0..7: k-chunk of 8 rows
  int nq = tid & 31;                       // n-col group of 4
  int n4 = nq << 2;

  f32x4 acc[4][4];
  #pragma unroll
  for (int i = 0; i < 4; ++i)
    #pragma unroll
    for (int j = 0; j < 4; ++j) acc[i][j] = (f32x4){0.f,0.f,0.f,0.f};

  auto stageA = [&](int buf, int k0){
    #pragma unroll
    for (int i = 0; i < 4; ++i){
      int cell = i*256 + tid;
      int row = cell >> 3, cc = cell & 7;
      int kg = k0 + ((cc ^ (row & 7)) << 3);
      __builtin_amdgcn_global_load_lds(
        (const __attribute__((address_space(1))) void*)(Ab + (size_t)row*lda + kg),
        (__attribute__((address_space(3))) void*)(&sA[buf][cell<<3]), 16, 0, 0);
    }
  };

  // B bf16 [K][N]: 8 rows x 4 cols per thread, uint2 (8B) per row
  auto stageB_load = [&](int k0g, uint2* F){
    const __hip_bfloat16* p = Bb + (size_t)(k0g + (kq<<3))*ldn + n4;
    #pragma unroll
    for (int rr = 0; rr < 8; ++rr)
      F[rr] = *reinterpret_cast<const uint2*>(p + (size_t)rr*ldn);
  };
  auto stageB_write = [&](int buf, const uint2* F){
    #pragma unroll
    for (int j = 0; j < 4; ++j){
      int n = n4 + j;
      int cell = (kq ^ (n >> 3) ^ n) & 7;
      auto US = [&](int rr)->uint32_t{
        return (((const uint32_t*)&F[rr])[j >> 1] >> ((j & 1) * 16)) & 0xffffu;
      };
      uint4 d;
      d.x = US(0) | (US(1) << 16);
      d.y = US(2) | (US(3) << 16);
      d.z = US(4) | (US(5) << 16);
      d.w = US(6) | (US(7) << 16);
      *reinterpret_cast<uint4*>(&sB[buf][(n<<6) + (cell<<3)]) = d;
    }
  };

  uint2 F[8];
  stageB_load(kb, F);
  stageA(0, kb);
  stageB_write(0, F);
  __syncthreads();

  for (int t = 0; t < nk; ++t){
    if (t+1 < nk){
      stageB_load(kb + ((t+1)<<6), F);
      stageA((t+1)&1, kb + ((t+1)<<6));
    }
    const char* baseA = (const char*)(&sA[t&1][0]);
    const char* baseB = (const char*)(&sB[t&1][0]);
    int rA = (wr<<6) + (lane & 15);
    int rB = (wc<<6) + (lane & 15);
    #pragma unroll
    for (int kk = 0; kk < 2; ++kk){
      int koffA = ((((kk<<5) + ((lane>>4)<<3)) << 1)) ^ ((lane & 7) << 4);
      bf16x8 av[4], bv[4];
      #pragma unroll
      for (int f = 0; f < 4; ++f){
        int rowA = rA + f*16;
        av[f] = *reinterpret_cast<const bf16x8*>(baseA + (size_t)rowA*128 + koffA);
        int rowB = rB + f*16;
        int cellB = (((kk<<2) + (lane>>4)) ^ (rowB >> 3) ^ rowB) & 7;
        bv[f] = *reinterpret_cast<const bf16x8*>(baseB + (size_t)rowB*128 + (cellB<<4));
      }
      #pragma unroll
      for (int i = 0; i < 4; ++i)
        #pragma unroll
        for (int j = 0; j < 4; ++j)
          acc[i][j] = __builtin_amdgcn_mfma_f32_16x16x32_bf16(av[i], bv[j], acc[i][j], 0, 0, 0);
    }
    if (t+1 < nk) stageB_write((t+1)&1, F);
    __syncthreads();
  }

  // epilogue; C/D layout (m89-verified): col = lane&15, row = (lane>>4)*4 + reg
  #pragma unroll
  for (int i = 0; i < 4; ++i){
    int rbase = (mt<<7) + (wr<<6) + (i<<4) + ((lane>>4)<<2);
    #pragma unroll
    for (int j = 0; j < 4; ++j){
      int colp = (wc<<6) + (j<<4) + (lane & 15);
      #pragma unroll
      for (int qq = 0; qq < 4; ++qq){
        int r = rbase + qq;
        float v = acc[i][j][qq];
        if constexpr (EPI == EPI_SPLIT){
          int col = (nt<<7) + colp;
          outf[(size_t)kzi*pstride + (size_t)r*ldo + col] = v;
        } else if constexpr (EPI == EPI_RES_BF16){
          int col = (nt<<7) + colp;
          int orig = rowmap[r];
          if (orig >= 0){
            v += bias[(size_t)s*biassub + col] + resid[(size_t)orig*ldres + col];
            outb[(size_t)r*ldo + col] = __float2bfloat16(v);
          }
        } else { // EPI_HEADS: store to partial buffer (concat col space)
          int col = (ntl<<7) + colp;
          outf[(size_t)kzi*pstride + (size_t)r*ldo + col] = v;
        }
      }
    }
  }
}

// ---------------- T1 = gelu(sum_p T1p + db[s])  (bf16) ----------------
template<int NPART>
__global__ void t1_epilogue(const float* __restrict__ Tp, const float* __restrict__ db,
                            const int* __restrict__ rowmap, const int* __restrict__ tileS,
                            __hip_bfloat16* __restrict__ T1){
  int idx = blockIdx.x*256 + threadIdx.x;
  int r = idx >> 7, c = idx & 127;
  float v = 0.f;
  if (rowmap[r] >= 0){
    int s = tileS[r >> 7];
    float acc = 0.f;
    #pragma unroll
    for (int p = 0; p < NPART; ++p) acc += Tp[(size_t)p*MP*BOT + idx];
    v = gelu_exact(acc + db[s*BOT + c]);
  }
  T1[idx] = __float2bfloat16(v);
}

// ---------------- row LN over summed partials (+linear bias) + gelu (+residual) ------
template<int RES, int NPART>
__global__ void ln_gelu_kernel(const float* __restrict__ Zp, size_t pstride,
                               const float* __restrict__ g,
                               const float* __restrict__ b, int gsub,
                               const float* __restrict__ lb,
                               const int* __restrict__ tileS, const int* __restrict__ rowmap,
                               float* __restrict__ Xf, __hip_bfloat16* __restrict__ Xb){
  int r = blockIdx.x, tid = threadIdx.x;
  size_t rowoff = (size_t)r * H;
  int c0 = tid << 3;
  int orig = rowmap[r];
  if (orig < 0){
    float4 zf = {0.f,0.f,0.f,0.f};
    *reinterpret_cast<float4*>(Xf + rowoff + c0)     = zf;
    *reinterpret_cast<float4*>(Xf + rowoff + c0 + 4) = zf;
    uint4 zu = {0u,0u,0u,0u};
    *reinterpret_cast<uint4*>(Xb + rowoff + c0) = zu;
    return;
  }
  int si = gsub ? tileS[r>>7] : 0;
  const float* gp  = g  + (size_t)si*gsub;
  const float* bp  = b  + (size_t)si*gsub;
  const float* lbp = lb + (size_t)si*gsub;
  float z[8];
  #pragma unroll
  for (int j = 0; j < 8; ++j) z[j] = lbp[c0+j];
  #pragma unroll
  for (int p = 0; p < NPART; ++p){
    float4 v1 = *reinterpret_cast<const float4*>(Zp + p*pstride + rowoff + c0);
    float4 v2 = *reinterpret_cast<const float4*>(Zp + p*pstride + rowoff + c0 + 4);
    z[0]+=v1.x; z[1]+=v1.y; z[2]+=v1.z; z[3]+=v1.w;
    z[4]+=v2.x; z[5]+=v2.y; z[6]+=v2.z; z[7]+=v2.w;
  }
  float s1 = 0.f, s2 = 0.f;
  #pragma unroll
  for (int j = 0; j < 8; ++j){ s1 += z[j]; s2 += z[j]*z[j]; }
  #pragma unroll
  for (int m = 32; m >= 1; m >>= 1){ s1 += __shfl_xor(s1, m); s2 += __shfl_xor(s2, m); }
  __shared__ float red[4][2];
  int wv = tid >> 6, lane = tid & 63;
  if (lane == 0){ red[wv][0] = s1; red[wv][1] = s2; }
  __syncthreads();
  s1 = red[0][0]+red[1][0]+red[2][0]+red[3][0];
  s2 = red[0][1]+red[1][1]+red[2][1]+red[3][1];
  const float invH = 1.f / (float)H;
  float mu  = s1 * invH;
  float var = s2 * invH - mu*mu;
  float rs  = rsqrtf(var + 1e-5f);
  float o[8];
  #pragma unroll
  for (int j = 0; j < 8; ++j){
    float t = (z[j]-mu)*rs*gp[c0+j] + bp[c0+j];
    o[j] = gelu_exact(t);
  }
  if constexpr (RES){
    float4 x1 = *reinterpret_cast<const float4*>(Xf + rowoff + c0);
    float4 x2 = *reinterpret_cast<const float4*>(Xf + rowoff + c0 + 4);
    o[0]+=x1.x; o[1]+=x1.y; o[2]+=x1.z; o[3]+=x1.w;
    o[4]+=x2.x; o[5]+=x2.y; o[6]+=x2.z; o[7]+=x2.w;
  }
  float4 w1 = {o[0],o[1],o[2],o[3]}, w2 = {o[4],o[5],o[6],o[7]};
  *reinterpret_cast<float4*>(Xf + rowoff + c0)     = w1;
  *reinterpret_cast<float4*>(Xf + rowoff + c0 + 4) = w2;
  __hip_bfloat16 ob[8];
  #pragma unroll
  for (int j = 0; j < 8; ++j) ob[j] = __float2bfloat16(o[j]);
  *reinterpret_cast<uint4*>(Xb + rowoff + c0) = *reinterpret_cast<const uint4*>(ob);
}

// ---------------- heads combine: sum 2 partials + bias, scatter to original rows ------
__global__ void head_combine(const float* __restrict__ Hp, size_t pstride,
                             const float* __restrict__ img_b, const float* __restrict__ txt_b,
                             const int* __restrict__ rowmap,
                             float* __restrict__ oimg, float* __restrict__ otxt){
  int r = blockIdx.x;
  int orig = rowmap[r];
  if (orig < 0) return;
  int col = threadIdx.x << 2;                    // 384 threads x 4 cols = 1536
  size_t base = (size_t)r*(IMG+TXT) + col;
  float4 v0 = *reinterpret_cast<const float4*>(Hp + base);
  float4 v1 = *reinterpret_cast<const float4*>(Hp + pstride + base);
  float4 bb = (col < IMG)
            ? *reinterpret_cast<const float4*>(img_b + col)
            : *reinterpret_cast<const float4*>(txt_b + (col - IMG));
  float4 o = {v0.x+v1.x+bb.x, v0.y+v1.y+bb.y, v0.z+v1.z+bb.z, v0.w+v1.w+bb.w};
  if (col < IMG) *reinterpret_cast<float4*>(oimg + (size_t)orig*IMG + col) = o;
  else           *reinterpret_cast<float4*>(otxt + (size_t)orig*TXT + (col-IMG)) = o;
}

// ------------------------------------------------------------------------------
extern "C" void kernel_launch(void* const* d_in, const int* in_sizes, int n_in,
                              void* d_out, int out_size, void* d_ws, size_t ws_size,
                              hipStream_t stream){
  (void)in_sizes; (void)n_in; (void)out_size; (void)ws_size;
  const float* vox       = (const float*)d_in[0];
  const int*   ids       = (const int*)  d_in[1];
  const float* ad_down_w = (const float*)d_in[2];
  const float* ad_down_b = (const float*)d_in[3];
  const float* ad_up_w   = (const float*)d_in[4];
  const float* ad_up_b   = (const float*)d_in[5];
  const float* enc_w     = (const float*)d_in[6];
  const float* enc_b     = (const float*)d_in[7];
  const float* enc_ln_g  = (const float*)d_in[8];
  const float* enc_ln_bb = (const float*)d_in[9];
  const float* bb_w      = (const float*)d_in[10];
  const float* bb_b      = (const float*)d_in[11];
  const float* bb_ln_g   = (const float*)d_in[12];
  const float* bb_ln_b   = (const float*)d_in[13];
  const float* img_w     = (const float*)d_in[14];
  const float* img_b     = (const float*)d_in[15];
  const float* txt_w     = (const float*)d_in[16];
  const float* txt_b     = (const float*)d_in[17];
  float* out = (float*)d_out;

  // bf16 weight pool segment sizes (elements)
  const size_t N_DOWN = (size_t)SUBJ*IN*BOT;
  const size_t N_UP   = (size_t)SUBJ*BOT*IN;
  const size_t N_ENC  = (size_t)SUBJ*IN*H;
  const size_t N_BB   = (size_t)DEPTH*H*H;
  const size_t N_IMG  = (size_t)H*IMG;
  const size_t N_TXT  = (size_t)H*TXT;

  char* wp = (char*)d_ws;
  auto alloc = [&](size_t bytes)->char*{ char* p = wp; wp += (bytes + 255) & ~(size_t)255; return p; };
  int* rowmap = (int*)alloc(MP * sizeof(int));
  int* tileS  = (int*)alloc(MT * sizeof(int));
  __hip_bfloat16* Wbf = (__hip_bfloat16*)alloc((N_DOWN+N_UP+N_ENC+N_BB+N_IMG+N_TXT)*2);
  __hip_bfloat16* w_down = Wbf;
  __hip_bfloat16* w_up   = w_down + N_DOWN;
  __hip_bfloat16* w_enc  = w_up   + N_UP;
  __hip_bfloat16* w_bb   = w_enc  + N_ENC;
  __hip_bfloat16* w_img  = w_bb   + N_BB;
  __hip_bfloat16* w_txt  = w_img  + N_IMG;
  __hip_bfloat16* Vs    = (__hip_bfloat16*)alloc((size_t)MP*IN*2);
  float* T1p            = (float*)alloc((size_t)16*MP*BOT*4);
  __hip_bfloat16* T1    = (__hip_bfloat16*)alloc((size_t)MP*BOT*2);
  __hip_bfloat16* Hs    = (__hip_bfloat16*)alloc((size_t)MP*IN*2);
  float* Zp             = (float*)alloc((size_t)4*MP*H*4);
  float* Hp             = Zp;               // alias: Zp dead before heads GEMM writes Hp
  float* Xf             = (float*)alloc((size_t)MP*H*4);
  __hip_bfloat16* Xb    = (__hip_bfloat16*)alloc((size_t)MP*H*2);

  const size_t ZPS = (size_t)MP*H;
  const size_t TPS = (size_t)MP*BOT;
  const size_t HPS = (size_t)MP*(IMG+TXT);

  // weight conversion pass (one chunk per thread; NT loads of dead fp32 source)
  CvtParams cp;
  size_t off = 0;
  cp.s[0] = {ad_down_w, off}; off += N_DOWN;
  cp.s[1] = {ad_up_w,   off}; off += N_UP;
  cp.s[2] = {enc_w,     off}; off += N_ENC;
  cp.s[3] = {bb_w,      off}; off += N_BB;
  cp.s[4] = {img_w,     off}; off += N_IMG;
  cp.s[5] = {txt_w,     off}; off += N_TXT;
  cp.total_items = off >> 4;                // 16 elements per item
  int cvt_blocks = (int)((cp.total_items + 255) / 256);
  convert_weights<<<cvt_blocks, 256, 0, stream>>>(cp, Wbf);

  sort_kernel<<<1, 1024, 0, stream>>>(ids, rowmap, tileS);
  gather_voxels<<<MP, 256, 0, stream>>>(vox, rowmap, Vs);

  // K1: adapter down. NT=1, KZ=16 (nx=1, qnt=1, ksplit=256, nk=4), grid 176.
  gemm_bf16<EPI_SPLIT,1><<<MT*16, 256, 0, stream>>>(
      Vs, IN, w_down, BOT, (long long)IN*BOT, tileS, rowmap, 1, 1, 256,
      nullptr, 0, nullptr, 0, T1p, nullptr, BOT, TPS, nullptr);
  t1_epilogue<16><<<MP*BOT/256, 256, 0, stream>>>(T1p, ad_down_b, rowmap, tileS, T1);

  // K2: adapter up + residual. NT=32, KZ=1 (nx=8, qnt=4, ksplit=128), grid 352.
  gemm_bf16<EPI_RES_BF16,2><<<MT*32, 256, 0, stream>>>(
      T1, BOT, w_up, IN, (long long)BOT*IN, tileS, rowmap, 8, 4, 128,
      ad_up_b, IN, vox, IN, nullptr, Hs, IN, 0, nullptr);

  // K3: encoder. NT=16, KZ=4 (nx=2, qnt=8, ksplit=1024, nk=16), grid 704.
  gemm_bf16<EPI_SPLIT,3><<<MT*8*8, 256, 0, stream>>>(
      Hs, IN, w_enc, H, (long long)IN*H, tileS, rowmap, 2, 8, 1024,
      nullptr, 0, nullptr, 0, Zp, nullptr, H, ZPS, nullptr);
  ln_gelu_kernel<0,4><<<MP, 256, 0, stream>>>(Zp, ZPS, enc_ln_g, enc_ln_bb, H, enc_b,
                                              tileS, rowmap, Xf, Xb);

  // backbone: 6 x (NT=16, KZ=2 (nx=4, qnt=4, ksplit=1024), grid 352)
  for (int d = 0; d < DEPTH; ++d){
    gemm_bf16<EPI_SPLIT,4><<<MT*4*8, 256, 0, stream>>>(
        Xb, H, w_bb + (size_t)d*H*H, H, 0, tileS, rowmap, 4, 4, 1024,
        nullptr, 0, nullptr, 0, Zp, nullptr, H, ZPS, nullptr);
    ln_gelu_kernel<1,2><<<MP, 256, 0, stream>>>(Zp, ZPS, bb_ln_g + (size_t)d*H,
                                                bb_ln_b + (size_t)d*H, 0, bb_b + (size_t)d*H,
                                                tileS, rowmap, Xf, Xb);
  }

  // heads: ONE gemm (img cols 0..5, txt 6..11), NT=12, KZ=2 (nx=4, qnt=3), grid 264.
  gemm_bf16<EPI_HEADS,5><<<MT*3*8, 256, 0, stream>>>(
      Xb, H, w_img, IMG, 0, tileS, rowmap, 4, 3, 1024,
      nullptr, 0, nullptr, 0, Hp, nullptr, IMG+TXT, HPS, w_txt);
  head_combine<<<MP, 384, 0, stream>>>(Hp, HPS, img_b, txt_b, rowmap,
                                       out, out + (size_t)BATCH*IMG);
}

// Round 14
// 461.648 us; speedup vs baseline: 1.2798x; 1.0161x over previous
//
#include <hip/hip_runtime.h>
#include <hip/hip_bf16.h>
#include <stdint.h>

typedef __bf16 bf16x8 __attribute__((ext_vector_type(8)));
typedef float  f32x4  __attribute__((ext_vector_type(4)));

#define DEV __device__ __forceinline__

constexpr int SUBJ  = 4;
constexpr int IN    = 4096;
constexpr int H     = 2048;
constexpr int DEPTH = 6;
constexpr int BATCH = 1024;
constexpr int BOT   = 128;
constexpr int IMG   = 768;
constexpr int TXT   = 768;
constexpr int MP    = 1408;   // padded sorted rows
constexpr int MT    = 11;     // MP/128 row tiles

DEV float gelu_exact(float x){ return 0.5f*x*(1.0f + erff(x*0.70710678118654752440f)); }

DEV uint16_t bf16_bits(float x){
  __hip_bfloat16 h = __float2bfloat16(x);
  return *reinterpret_cast<uint16_t*>(&h);
}
DEV float bfu(uint32_t w, int hi){
  uint32_t x = hi ? (w & 0xffff0000u) : (w << 16);
  return __uint_as_float(x);
}
DEV float bf2f(uint16_t u){ uint32_t x = (uint32_t)u << 16; return __uint_as_float(x); }

// ---------------- one-shot fp32 -> bf16 weight conversion (same layout) ----------------
// 32 elements per thread: 8 independent float4 loads (max MLP), 4 uint4 stores.
// Normal (cached) loads — R13 showed NT loads inflate FETCH by ~8%.
struct CvtSeg { const float* src; size_t dst_off; };
struct CvtParams { CvtSeg s[6]; size_t total_items; };

__global__ void convert_weights(CvtParams p, __hip_bfloat16* __restrict__ dst){
  size_t it = (size_t)blockIdx.x*blockDim.x + threadIdx.x;
  if (it >= p.total_items) return;
  size_t e = it << 5;                       // 32 elements per thread
  int si = 0;
  #pragma unroll
  for (int i = 1; i < 6; ++i) if (e >= p.s[i].dst_off) si = i;
  const float* s = p.s[si].src + (e - p.s[si].dst_off);
  float4 f[8];
  #pragma unroll
  for (int i = 0; i < 8; ++i) f[i] = *reinterpret_cast<const float4*>(s + 4*i);
  uint16_t o[32];
  #pragma unroll
  for (int i = 0; i < 8; ++i){
    o[4*i+0] = bf16_bits(f[i].x); o[4*i+1] = bf16_bits(f[i].y);
    o[4*i+2] = bf16_bits(f[i].z); o[4*i+3] = bf16_bits(f[i].w);
  }
  #pragma unroll
  for (int i = 0; i < 4; ++i)
    *reinterpret_cast<uint4*>(dst + e + 8*i) = *reinterpret_cast<const uint4*>(&o[8*i]);
}

// ---------------- subject counting-sort (1 block, 1024 threads) ----------------
__global__ void sort_kernel(const int* __restrict__ ids, int* __restrict__ rowmap,
                            int* __restrict__ tileS){
  __shared__ int hist[16][4];
  __shared__ int basew[16][4];
  __shared__ int pstart[5];
  int tid = threadIdx.x;
  if (tid < MP) rowmap[tid] = -1;
  if (tid + 1024 < MP) rowmap[tid + 1024] = -1;
  int w = tid >> 6, lane = tid & 63;
  int my = ids[tid];
  unsigned long long mymask = 0ull;
  #pragma unroll
  for (int s = 0; s < 4; ++s){
    unsigned long long m = __ballot(my == s);
    if (lane == 0) hist[w][s] = (int)__popcll(m);
    if (s == my) mymask = m;
  }
  int myrank = (int)__popcll(mymask & ((1ull << lane) - 1ull));
  __syncthreads();
  if (tid == 0){
    for (int s = 0; s < 4; ++s){
      int run = 0;
      for (int ww = 0; ww < 16; ++ww){ basew[ww][s] = run; run += hist[ww][s]; }
      hist[0][s] = run;
    }
    pstart[0] = 0;
    for (int s = 0; s < 4; ++s) pstart[s+1] = pstart[s] + ((hist[0][s] + 127) & ~127);
  }
  __syncthreads();
  int pos = pstart[my] + basew[w][my] + myrank;
  rowmap[pos] = tid;
  if (tid < MT){
    int row0 = tid << 7, s = -1;
    for (int ss = 0; ss < 4; ++ss) if (row0 >= pstart[ss] && row0 < pstart[ss+1]) s = ss;
    tileS[tid] = s;
  }
}

// ---------------- gather voxels into sorted order, fp32 -> bf16 ----------------
__global__ void gather_voxels(const float* __restrict__ vox, const int* __restrict__ rowmap,
                              __hip_bfloat16* __restrict__ Vs){
  int r = blockIdx.x, tid = threadIdx.x;
  int orig = rowmap[r];
  #pragma unroll
  for (int i = 0; i < 4; ++i){
    int c = (i*256 + tid) << 2;
    float4 v = {0.f,0.f,0.f,0.f};
    if (orig >= 0) v = *reinterpret_cast<const float4*>(vox + (size_t)orig*IN + c);
    __hip_bfloat16 o[4] = {__float2bfloat16(v.x), __float2bfloat16(v.y),
                           __float2bfloat16(v.z), __float2bfloat16(v.w)};
    *reinterpret_cast<uint2*>(Vs + (size_t)r*IN + c) = *reinterpret_cast<const uint2*>(o);
  }
}

// ---------------- 128x128 tile MFMA GEMM, bf16 B [K][N] (pre-converted) --------------
// Decode: xcd=b&7; r=b>>3; mt=r%MT; q=r/MT;
//         kzi = xcd/nx + (q/qnt)*(8/nx);  nt = (q%qnt)*nx + xcd%nx.
// Split-K partials are BF16 (fp32 accumulate, one RNE round): halves partial traffic.
enum { EPI_SPLIT = 0, EPI_RES_BF16 = 1, EPI_HEADS = 3 };

template<int EPI, int TAG>
__global__ __launch_bounds__(256, 2)
void gemm_bf16(const __hip_bfloat16* __restrict__ A, int lda,
               const __hip_bfloat16* __restrict__ Bw, int ldn, long long wsub,
               const int* __restrict__ tileS, const int* __restrict__ rowmap,
               int nx, int qnt, int ksplit,
               const float* __restrict__ bias, int biassub,
               const float* __restrict__ resid, int ldres,
               __hip_bfloat16* __restrict__ outb, int ldo,
               size_t pstride, const __hip_bfloat16* __restrict__ Bw2)
{
  int b   = blockIdx.x;
  int xcd = b & 7;
  int r0  = b >> 3;
  int mt  = r0 % MT;
  int q   = r0 / MT;
  int kzi = xcd / nx + (q / qnt) * (8 / nx);
  int nt  = (q % qnt) * nx + (xcd % nx);

  int s = tileS[mt];
  if (s < 0) return;                       // inactive (pad) row tile
  const __hip_bfloat16* Ab = A + (size_t)mt*128*lda;

  const __hip_bfloat16* Bb;
  int ntl = nt;
  if constexpr (EPI == EPI_HEADS){
    if (nt < 6){ Bb = Bw  + (size_t)nt*128; }
    else       { Bb = Bw2 + (size_t)(nt-6)*128; }
    ntl = nt;                              // col in concat [0,1536)
  } else {
    Bb = Bw + (size_t)s*wsub + (size_t)nt*128;
  }

  int kb = kzi * ksplit;
  int nk = ksplit >> 6;

  __shared__ __hip_bfloat16 sA[2][128*64];
  __shared__ __hip_bfloat16 sB[2][128*64];

  int tid = threadIdx.x;
  int lane = tid & 63;
  int wv = tid >> 6, wr = wv >> 1, wc = wv & 1;

  int kq = tid >> 5;                       // 0..7: k-chunk of 8 rows
  int nq = tid & 31;                       // n-col group of 4
  int n4 = nq << 2;

  f32x4 acc[4][4];
  #pragma unroll
  for (int i = 0; i < 4; ++i)
    #pragma unroll
    for (int j = 0; j < 4; ++j) acc[i][j] = (f32x4){0.f,0.f,0.f,0.f};

  auto stageA = [&](int buf, int k0){
    #pragma unroll
    for (int i = 0; i < 4; ++i){
      int cell = i*256 + tid;
      int row = cell >> 3, cc = cell & 7;
      int kg = k0 + ((cc ^ (row & 7)) << 3);
      __builtin_amdgcn_global_load_lds(
        (const __attribute__((address_space(1))) void*)(Ab + (size_t)row*lda + kg),
        (__attribute__((address_space(3))) void*)(&sA[buf][cell<<3]), 16, 0, 0);
    }
  };

  // B bf16 [K][N]: 8 rows x 4 cols per thread, uint2 (8B) per row
  auto stageB_load = [&](int k0g, uint2* F){
    const __hip_bfloat16* p = Bb + (size_t)(k0g + (kq<<3))*ldn + n4;
    #pragma unroll
    for (int rr = 0; rr < 8; ++rr)
      F[rr] = *reinterpret_cast<const uint2*>(p + (size_t)rr*ldn);
  };
  auto stageB_write = [&](int buf, const uint2* F){
    #pragma unroll
    for (int j = 0; j < 4; ++j){
      int n = n4 + j;
      int cell = (kq ^ (n >> 3) ^ n) & 7;
      auto US = [&](int rr)->uint32_t{
        return (((const uint32_t*)&F[rr])[j >> 1] >> ((j & 1) * 16)) & 0xffffu;
      };
      uint4 d;
      d.x = US(0) | (US(1) << 16);
      d.y = US(2) | (US(3) << 16);
      d.z = US(4) | (US(5) << 16);
      d.w = US(6) | (US(7) << 16);
      *reinterpret_cast<uint4*>(&sB[buf][(n<<6) + (cell<<3)]) = d;
    }
  };

  uint2 F[8];
  stageB_load(kb, F);
  stageA(0, kb);
  stageB_write(0, F);
  __syncthreads();

  for (int t = 0; t < nk; ++t){
    if (t+1 < nk){
      stageB_load(kb + ((t+1)<<6), F);
      stageA((t+1)&1, kb + ((t+1)<<6));
    }
    const char* baseA = (const char*)(&sA[t&1][0]);
    const char* baseB = (const char*)(&sB[t&1][0]);
    int rA = (wr<<6) + (lane & 15);
    int rB = (wc<<6) + (lane & 15);
    #pragma unroll
    for (int kk = 0; kk < 2; ++kk){
      int koffA = ((((kk<<5) + ((lane>>4)<<3)) << 1)) ^ ((lane & 7) << 4);
      bf16x8 av[4], bv[4];
      #pragma unroll
      for (int f = 0; f < 4; ++f){
        int rowA = rA + f*16;
        av[f] = *reinterpret_cast<const bf16x8*>(baseA + (size_t)rowA*128 + koffA);
        int rowB = rB + f*16;
        int cellB = (((kk<<2) + (lane>>4)) ^ (rowB >> 3) ^ rowB) & 7;
        bv[f] = *reinterpret_cast<const bf16x8*>(baseB + (size_t)rowB*128 + (cellB<<4));
      }
      #pragma unroll
      for (int i = 0; i < 4; ++i)
        #pragma unroll
        for (int j = 0; j < 4; ++j)
          acc[i][j] = __builtin_amdgcn_mfma_f32_16x16x32_bf16(av[i], bv[j], acc[i][j], 0, 0, 0);
    }
    if (t+1 < nk) stageB_write((t+1)&1, F);
    __syncthreads();
  }

  // epilogue; C/D layout (m89-verified): col = lane&15, row = (lane>>4)*4 + reg
  #pragma unroll
  for (int i = 0; i < 4; ++i){
    int rbase = (mt<<7) + (wr<<6) + (i<<4) + ((lane>>4)<<2);
    #pragma unroll
    for (int j = 0; j < 4; ++j){
      int colp = (wc<<6) + (j<<4) + (lane & 15);
      #pragma unroll
      for (int qq = 0; qq < 4; ++qq){
        int r = rbase + qq;
        float v = acc[i][j][qq];
        if constexpr (EPI == EPI_SPLIT){
          int col = (nt<<7) + colp;
          outb[(size_t)kzi*pstride + (size_t)r*ldo + col] = __float2bfloat16(v);
        } else if constexpr (EPI == EPI_RES_BF16){
          int col = (nt<<7) + colp;
          int orig = rowmap[r];
          if (orig >= 0){
            v += bias[(size_t)s*biassub + col] + resid[(size_t)orig*ldres + col];
            outb[(size_t)r*ldo + col] = __float2bfloat16(v);
          }
        } else { // EPI_HEADS: bf16 partial (concat col space)
          int col = (ntl<<7) + colp;
          outb[(size_t)kzi*pstride + (size_t)r*ldo + col] = __float2bfloat16(v);
        }
      }
    }
  }
}

// ---------------- T1 = gelu(sum_p T1p + db[s])  (bf16 partials) ----------------
template<int NPART>
__global__ void t1_epilogue(const __hip_bfloat16* __restrict__ Tp, const float* __restrict__ db,
                            const int* __restrict__ rowmap, const int* __restrict__ tileS,
                            __hip_bfloat16* __restrict__ T1){
  int idx = blockIdx.x*256 + threadIdx.x;
  int r = idx >> 7, c = idx & 127;
  float v = 0.f;
  if (rowmap[r] >= 0){
    int s = tileS[r >> 7];
    float acc = 0.f;
    #pragma unroll
    for (int p = 0; p < NPART; ++p)
      acc += bf2f(*reinterpret_cast<const uint16_t*>(Tp + (size_t)p*MP*BOT + idx));
    v = gelu_exact(acc + db[s*BOT + c]);
  }
  T1[idx] = __float2bfloat16(v);
}

// ---------------- row LN over summed bf16 partials (+linear bias) + gelu (+residual) --
template<int RES, int NPART>
__global__ void ln_gelu_kernel(const __hip_bfloat16* __restrict__ Zp, size_t pstride,
                               const float* __restrict__ g,
                               const float* __restrict__ b, int gsub,
                               const float* __restrict__ lb,
                               const int* __restrict__ tileS, const int* __restrict__ rowmap,
                               float* __restrict__ Xf, __hip_bfloat16* __restrict__ Xb){
  int r = blockIdx.x, tid = threadIdx.x;
  size_t rowoff = (size_t)r * H;
  int c0 = tid << 3;
  int orig = rowmap[r];
  if (orig < 0){
    float4 zf = {0.f,0.f,0.f,0.f};
    *reinterpret_cast<float4*>(Xf + rowoff + c0)     = zf;
    *reinterpret_cast<float4*>(Xf + rowoff + c0 + 4) = zf;
    uint4 zu = {0u,0u,0u,0u};
    *reinterpret_cast<uint4*>(Xb + rowoff + c0) = zu;
    return;
  }
  int si = gsub ? tileS[r>>7] : 0;
  const float* gp  = g  + (size_t)si*gsub;
  const float* bp  = b  + (size_t)si*gsub;
  const float* lbp = lb + (size_t)si*gsub;
  float z[8];
  #pragma unroll
  for (int j = 0; j < 8; ++j) z[j] = lbp[c0+j];
  #pragma unroll
  for (int p = 0; p < NPART; ++p){
    uint4 v = *reinterpret_cast<const uint4*>(Zp + p*pstride + rowoff + c0);
    z[0] += bfu(v.x,0); z[1] += bfu(v.x,1);
    z[2] += bfu(v.y,0); z[3] += bfu(v.y,1);
    z[4] += bfu(v.z,0); z[5] += bfu(v.z,1);
    z[6] += bfu(v.w,0); z[7] += bfu(v.w,1);
  }
  float s1 = 0.f, s2 = 0.f;
  #pragma unroll
  for (int j = 0; j < 8; ++j){ s1 += z[j]; s2 += z[j]*z[j]; }
  #pragma unroll
  for (int m = 32; m >= 1; m >>= 1){ s1 += __shfl_xor(s1, m); s2 += __shfl_xor(s2, m); }
  __shared__ float red[4][2];
  int wv = tid >> 6, lane = tid & 63;
  if (lane == 0){ red[wv][0] = s1; red[wv][1] = s2; }
  __syncthreads();
  s1 = red[0][0]+red[1][0]+red[2][0]+red[3][0];
  s2 = red[0][1]+red[1][1]+red[2][1]+red[3][1];
  const float invH = 1.f / (float)H;
  float mu  = s1 * invH;
  float var = s2 * invH - mu*mu;
  float rs  = rsqrtf(var + 1e-5f);
  float o[8];
  #pragma unroll
  for (int j = 0; j < 8; ++j){
    float t = (z[j]-mu)*rs*gp[c0+j] + bp[c0+j];
    o[j] = gelu_exact(t);
  }
  if constexpr (RES){
    float4 x1 = *reinterpret_cast<const float4*>(Xf + rowoff + c0);
    float4 x2 = *reinterpret_cast<const float4*>(Xf + rowoff + c0 + 4);
    o[0]+=x1.x; o[1]+=x1.y; o[2]+=x1.z; o[3]+=x1.w;
    o[4]+=x2.x; o[5]+=x2.y; o[6]+=x2.z; o[7]+=x2.w;
  }
  float4 w1 = {o[0],o[1],o[2],o[3]}, w2 = {o[4],o[5],o[6],o[7]};
  *reinterpret_cast<float4*>(Xf + rowoff + c0)     = w1;
  *reinterpret_cast<float4*>(Xf + rowoff + c0 + 4) = w2;
  __hip_bfloat16 ob[8];
  #pragma unroll
  for (int j = 0; j < 8; ++j) ob[j] = __float2bfloat16(o[j]);
  *reinterpret_cast<uint4*>(Xb + rowoff + c0) = *reinterpret_cast<const uint4*>(ob);
}

// ---------------- heads combine: sum 2 bf16 partials + bias, scatter -----------------
__global__ void head_combine(const __hip_bfloat16* __restrict__ Hp, size_t pstride,
                             const float* __restrict__ img_b, const float* __restrict__ txt_b,
                             const int* __restrict__ rowmap,
                             float* __restrict__ oimg, float* __restrict__ otxt){
  int r = blockIdx.x;
  int orig = rowmap[r];
  if (orig < 0) return;
  int col = threadIdx.x << 2;                    // 384 threads x 4 cols = 1536
  size_t base = (size_t)r*(IMG+TXT) + col;
  uint2 u0 = *reinterpret_cast<const uint2*>(Hp + base);
  uint2 u1 = *reinterpret_cast<const uint2*>(Hp + pstride + base);
  float4 acc;
  acc.x = bfu(u0.x,0) + bfu(u1.x,0);
  acc.y = bfu(u0.x,1) + bfu(u1.x,1);
  acc.z = bfu(u0.y,0) + bfu(u1.y,0);
  acc.w = bfu(u0.y,1) + bfu(u1.y,1);
  float4 bb = (col < IMG)
            ? *reinterpret_cast<const float4*>(img_b + col)
            : *reinterpret_cast<const float4*>(txt_b + (col - IMG));
  float4 o = {acc.x+bb.x, acc.y+bb.y, acc.z+bb.z, acc.w+bb.w};
  if (col < IMG) *reinterpret_cast<float4*>(oimg + (size_t)orig*IMG + col) = o;
  else           *reinterpret_cast<float4*>(otxt + (size_t)orig*TXT + (col-IMG)) = o;
}

// ------------------------------------------------------------------------------
extern "C" void kernel_launch(void* const* d_in, const int* in_sizes, int n_in,
                              void* d_out, int out_size, void* d_ws, size_t ws_size,
                              hipStream_t stream){
  (void)in_sizes; (void)n_in; (void)out_size; (void)ws_size;
  const float* vox       = (const float*)d_in[0];
  const int*   ids       = (const int*)  d_in[1];
  const float* ad_down_w = (const float*)d_in[2];
  const float* ad_down_b = (const float*)d_in[3];
  const float* ad_up_w   = (const float*)d_in[4];
  const float* ad_up_b   = (const float*)d_in[5];
  const float* enc_w     = (const float*)d_in[6];
  const float* enc_b     = (const float*)d_in[7];
  const float* enc_ln_g  = (const float*)d_in[8];
  const float* enc_ln_bb = (const float*)d_in[9];
  const float* bb_w      = (const float*)d_in[10];
  const float* bb_b      = (const float*)d_in[11];
  const float* bb_ln_g   = (const float*)d_in[12];
  const float* bb_ln_b   = (const float*)d_in[13];
  const float* img_w     = (const float*)d_in[14];
  const float* img_b     = (const float*)d_in[15];
  const float* txt_w     = (const float*)d_in[16];
  const float* txt_b     = (const float*)d_in[17];
  float* out = (float*)d_out;

  // bf16 weight pool segment sizes (elements)
  const size_t N_DOWN = (size_t)SUBJ*IN*BOT;
  const size_t N_UP   = (size_t)SUBJ*BOT*IN;
  const size_t N_ENC  = (size_t)SUBJ*IN*H;
  const size_t N_BB   = (size_t)DEPTH*H*H;
  const size_t N_IMG  = (size_t)H*IMG;
  const size_t N_TXT  = (size_t)H*TXT;

  char* wp = (char*)d_ws;
  auto alloc = [&](size_t bytes)->char*{ char* p = wp; wp += (bytes + 255) & ~(size_t)255; return p; };
  int* rowmap = (int*)alloc(MP * sizeof(int));
  int* tileS  = (int*)alloc(MT * sizeof(int));
  __hip_bfloat16* Wbf = (__hip_bfloat16*)alloc((N_DOWN+N_UP+N_ENC+N_BB+N_IMG+N_TXT)*2);
  __hip_bfloat16* w_down = Wbf;
  __hip_bfloat16* w_up   = w_down + N_DOWN;
  __hip_bfloat16* w_enc  = w_up   + N_UP;
  __hip_bfloat16* w_bb   = w_enc  + N_ENC;
  __hip_bfloat16* w_img  = w_bb   + N_BB;
  __hip_bfloat16* w_txt  = w_img  + N_IMG;
  __hip_bfloat16* Vs    = (__hip_bfloat16*)alloc((size_t)MP*IN*2);
  __hip_bfloat16* T1p   = (__hip_bfloat16*)alloc((size_t)16*MP*BOT*2);
  __hip_bfloat16* T1    = (__hip_bfloat16*)alloc((size_t)MP*BOT*2);
  __hip_bfloat16* Hs    = (__hip_bfloat16*)alloc((size_t)MP*IN*2);
  __hip_bfloat16* Zp    = (__hip_bfloat16*)alloc((size_t)4*MP*H*2);
  __hip_bfloat16* Hp    = Zp;               // alias: Zp dead before heads GEMM writes Hp
  float* Xf             = (float*)alloc((size_t)MP*H*4);
  __hip_bfloat16* Xb    = (__hip_bfloat16*)alloc((size_t)MP*H*2);

  const size_t ZPS = (size_t)MP*H;
  const size_t TPS = (size_t)MP*BOT;
  const size_t HPS = (size_t)MP*(IMG+TXT);

  // weight conversion pass (32 elem/thread, cached loads)
  CvtParams cp;
  size_t off = 0;
  cp.s[0] = {ad_down_w, off}; off += N_DOWN;
  cp.s[1] = {ad_up_w,   off}; off += N_UP;
  cp.s[2] = {enc_w,     off}; off += N_ENC;
  cp.s[3] = {bb_w,      off}; off += N_BB;
  cp.s[4] = {img_w,     off}; off += N_IMG;
  cp.s[5] = {txt_w,     off}; off += N_TXT;
  cp.total_items = off >> 5;                // 32 elements per item
  int cvt_blocks = (int)((cp.total_items + 255) / 256);
  convert_weights<<<cvt_blocks, 256, 0, stream>>>(cp, Wbf);

  sort_kernel<<<1, 1024, 0, stream>>>(ids, rowmap, tileS);
  gather_voxels<<<MP, 256, 0, stream>>>(vox, rowmap, Vs);

  // K1: adapter down. NT=1, KZ=16 (nx=1, qnt=1, ksplit=256, nk=4), grid 176.
  gemm_bf16<EPI_SPLIT,1><<<MT*16, 256, 0, stream>>>(
      Vs, IN, w_down, BOT, (long long)IN*BOT, tileS, rowmap, 1, 1, 256,
      nullptr, 0, nullptr, 0, T1p, BOT, TPS, nullptr);
  t1_epilogue<16><<<MP*BOT/256, 256, 0, stream>>>(T1p, ad_down_b, rowmap, tileS, T1);

  // K2: adapter up + residual. NT=32, KZ=1 (nx=8, qnt=4, ksplit=128), grid 352.
  gemm_bf16<EPI_RES_BF16,2><<<MT*32, 256, 0, stream>>>(
      T1, BOT, w_up, IN, (long long)BOT*IN, tileS, rowmap, 8, 4, 128,
      ad_up_b, IN, vox, IN, Hs, IN, 0, nullptr);

  // K3: encoder. NT=16, KZ=4 (nx=2, qnt=8, ksplit=1024, nk=16), grid 704.
  gemm_bf16<EPI_SPLIT,3><<<MT*8*8, 256, 0, stream>>>(
      Hs, IN, w_enc, H, (long long)IN*H, tileS, rowmap, 2, 8, 1024,
      nullptr, 0, nullptr, 0, Zp, H, ZPS, nullptr);
  ln_gelu_kernel<0,4><<<MP, 256, 0, stream>>>(Zp, ZPS, enc_ln_g, enc_ln_bb, H, enc_b,
                                              tileS, rowmap, Xf, Xb);

  // backbone: 6 x (NT=16, KZ=2 (nx=4, qnt=4, ksplit=1024), grid 352)
  for (int d = 0; d < DEPTH; ++d){
    gemm_bf16<EPI_SPLIT,4><<<MT*4*8, 256, 0, stream>>>(
        Xb, H, w_bb + (size_t)d*H*H, H, 0, tileS, rowmap, 4, 4, 1024,
        nullptr, 0, nullptr, 0, Zp, H, ZPS, nullptr);
    ln_gelu_kernel<1,2><<<MP, 256, 0, stream>>>(Zp, ZPS, bb_ln_g + (size_t)d*H,
                                                bb_ln_b + (size_t)d*H, 0, bb_b + (size_t)d*H,
                                                tileS, rowmap, Xf, Xb);
  }

  // heads: ONE gemm (img cols 0..5, txt 6..11), NT=12, KZ=2 (nx=4, qnt=3), grid 264.
  gemm_bf16<EPI_HEADS,5><<<MT*3*8, 256, 0, stream>>>(
      Xb, H, w_img, IMG, 0, tileS, rowmap, 4, 3, 1024,
      nullptr, 0, nullptr, 0, Hp, IMG+TXT, HPS, w_txt);
  head_combine<<<MP, 384, 0, stream>>>(Hp, HPS, img_b, txt_b, rowmap,
                                       out, out + (size_t)BATCH*IMG);
}

// Round 15
// 445.896 us; speedup vs baseline: 1.3250x; 1.0353x over previous
//
#include <hip/hip_runtime.h>
#include <hip/hip_bf16.h>
#include <stdint.h>

typedef __bf16 bf16x8 __attribute__((ext_vector_type(8)));
typedef float  f32x4  __attribute__((ext_vector_type(4)));
typedef float  vf4    __attribute__((ext_vector_type(4)));

#define DEV __device__ __forceinline__

constexpr int SUBJ  = 4;
constexpr int IN    = 4096;
constexpr int H     = 2048;
constexpr int DEPTH = 6;
constexpr int BATCH = 1024;
constexpr int BOT   = 128;
constexpr int IMG   = 768;
constexpr int TXT   = 768;
constexpr int MP    = 1408;   // padded sorted rows
constexpr int MT    = 11;     // MP/128 row tiles

DEV float gelu_exact(float x){ return 0.5f*x*(1.0f + erff(x*0.70710678118654752440f)); }

DEV uint16_t bf16_bits(float x){
  __hip_bfloat16 h = __float2bfloat16(x);
  return *reinterpret_cast<uint16_t*>(&h);
}
DEV float bfu(uint32_t w, int hi){
  uint32_t x = hi ? (w & 0xffff0000u) : (w << 16);
  return __uint_as_float(x);
}
DEV float bf2f(uint16_t u){ uint32_t x = (uint32_t)u << 16; return __uint_as_float(x); }

// ---------------- one-shot fp32 -> bf16 weight conversion (same layout) ----------------
// R13-measured-best config: 16 elem/thread, NT loads (dead fp32 source), cached stores
// (bf16 pool is re-read by every GEMM; mostly L3-resident). 98 us measured.
struct CvtSeg { const float* src; size_t dst_off; };
struct CvtParams { CvtSeg s[6]; size_t total_items; };

__global__ void convert_weights(CvtParams p, __hip_bfloat16* __restrict__ dst){
  size_t it = (size_t)blockIdx.x*blockDim.x + threadIdx.x;
  if (it >= p.total_items) return;
  size_t e = it << 4;                       // 16 elements per thread
  int si = 0;
  #pragma unroll
  for (int i = 1; i < 6; ++i) if (e >= p.s[i].dst_off) si = i;
  const float* s = p.s[si].src + (e - p.s[si].dst_off);
  vf4 a = __builtin_nontemporal_load(reinterpret_cast<const vf4*>(s));
  vf4 b = __builtin_nontemporal_load(reinterpret_cast<const vf4*>(s + 4));
  vf4 c = __builtin_nontemporal_load(reinterpret_cast<const vf4*>(s + 8));
  vf4 d = __builtin_nontemporal_load(reinterpret_cast<const vf4*>(s + 12));
  uint16_t o[16] = {bf16_bits(a.x), bf16_bits(a.y), bf16_bits(a.z), bf16_bits(a.w),
                    bf16_bits(b.x), bf16_bits(b.y), bf16_bits(b.z), bf16_bits(b.w),
                    bf16_bits(c.x), bf16_bits(c.y), bf16_bits(c.z), bf16_bits(c.w),
                    bf16_bits(d.x), bf16_bits(d.y), bf16_bits(d.z), bf16_bits(d.w)};
  *reinterpret_cast<uint4*>(dst + e)     = *reinterpret_cast<const uint4*>(&o[0]);
  *reinterpret_cast<uint4*>(dst + e + 8) = *reinterpret_cast<const uint4*>(&o[8]);
}

// ---------------- subject counting-sort (1 block, 1024 threads) ----------------
__global__ void sort_kernel(const int* __restrict__ ids, int* __restrict__ rowmap,
                            int* __restrict__ tileS){
  __shared__ int hist[16][4];
  __shared__ int basew[16][4];
  __shared__ int pstart[5];
  int tid = threadIdx.x;
  if (tid < MP) rowmap[tid] = -1;
  if (tid + 1024 < MP) rowmap[tid + 1024] = -1;
  int w = tid >> 6, lane = tid & 63;
  int my = ids[tid];
  unsigned long long mymask = 0ull;
  #pragma unroll
  for (int s = 0; s < 4; ++s){
    unsigned long long m = __ballot(my == s);
    if (lane == 0) hist[w][s] = (int)__popcll(m);
    if (s == my) mymask = m;
  }
  int myrank = (int)__popcll(mymask & ((1ull << lane) - 1ull));
  __syncthreads();
  if (tid == 0){
    for (int s = 0; s < 4; ++s){
      int run = 0;
      for (int ww = 0; ww < 16; ++ww){ basew[ww][s] = run; run += hist[ww][s]; }
      hist[0][s] = run;
    }
    pstart[0] = 0;
    for (int s = 0; s < 4; ++s) pstart[s+1] = pstart[s] + ((hist[0][s] + 127) & ~127);
  }
  __syncthreads();
  int pos = pstart[my] + basew[w][my] + myrank;
  rowmap[pos] = tid;
  if (tid < MT){
    int row0 = tid << 7, s = -1;
    for (int ss = 0; ss < 4; ++ss) if (row0 >= pstart[ss] && row0 < pstart[ss+1]) s = ss;
    tileS[tid] = s;
  }
}

// ---------------- gather voxels into sorted order, fp32 -> bf16 ----------------
__global__ void gather_voxels(const float* __restrict__ vox, const int* __restrict__ rowmap,
                              __hip_bfloat16* __restrict__ Vs){
  int r = blockIdx.x, tid = threadIdx.x;
  int orig = rowmap[r];
  #pragma unroll
  for (int i = 0; i < 4; ++i){
    int c = (i*256 + tid) << 2;
    float4 v = {0.f,0.f,0.f,0.f};
    if (orig >= 0) v = *reinterpret_cast<const float4*>(vox + (size_t)orig*IN + c);
    __hip_bfloat16 o[4] = {__float2bfloat16(v.x), __float2bfloat16(v.y),
                           __float2bfloat16(v.z), __float2bfloat16(v.w)};
    *reinterpret_cast<uint2*>(Vs + (size_t)r*IN + c) = *reinterpret_cast<const uint2*>(o);
  }
}

// ---------------- 128x128 tile MFMA GEMM, bf16 B [K][N] (pre-converted) --------------
// Decode: xcd=b&7; r=b>>3; mt=r%MT; q=r/MT;
//         kzi = xcd/nx + (q/qnt)*(8/nx);  nt = (q%qnt)*nx + xcd%nx.
// Split-K partials are BF16 (fp32 accumulate, one RNE round).
enum { EPI_SPLIT = 0, EPI_RES_BF16 = 1, EPI_HEADS = 3 };

template<int EPI, int TAG>
__global__ __launch_bounds__(256, 2)
void gemm_bf16(const __hip_bfloat16* __restrict__ A, int lda,
               const __hip_bfloat16* __restrict__ Bw, int ldn, long long wsub,
               const int* __restrict__ tileS, const int* __restrict__ rowmap,
               int nx, int qnt, int ksplit,
               const float* __restrict__ bias, int biassub,
               const float* __restrict__ resid, int ldres,
               __hip_bfloat16* __restrict__ outb, int ldo,
               size_t pstride, const __hip_bfloat16* __restrict__ Bw2)
{
  int b   = blockIdx.x;
  int xcd = b & 7;
  int r0  = b >> 3;
  int mt  = r0 % MT;
  int q   = r0 / MT;
  int kzi = xcd / nx + (q / qnt) * (8 / nx);
  int nt  = (q % qnt) * nx + (xcd % nx);

  int s = tileS[mt];
  if (s < 0) return;                       // inactive (pad) row tile
  const __hip_bfloat16* Ab = A + (size_t)mt*128*lda;

  const __hip_bfloat16* Bb;
  int ntl = nt;
  if constexpr (EPI == EPI_HEADS){
    if (nt < 6){ Bb = Bw  + (size_t)nt*128; }
    else       { Bb = Bw2 + (size_t)(nt-6)*128; }
    ntl = nt;                              // col in concat [0,1536)
  } else {
    Bb = Bw + (size_t)s*wsub + (size_t)nt*128;
  }

  int kb = kzi * ksplit;
  int nk = ksplit >> 6;

  __shared__ __hip_bfloat16 sA[2][128*64];
  __shared__ __hip_bfloat16 sB[2][128*64];

  int tid = threadIdx.x;
  int lane = tid & 63;
  int wv = tid >> 6, wr = wv >> 1, wc = wv & 1;

  int kq = tid >> 5;                       // 0..7: k-chunk of 8 rows
  int nq = tid & 31;                       // n-col group of 4
  int n4 = nq << 2;

  f32x4 acc[4][4];
  #pragma unroll
  for (int i = 0; i < 4; ++i)
    #pragma unroll
    for (int j = 0; j < 4; ++j) acc[i][j] = (f32x4){0.f,0.f,0.f,0.f};

  auto stageA = [&](int buf, int k0){
    #pragma unroll
    for (int i = 0; i < 4; ++i){
      int cell = i*256 + tid;
      int row = cell >> 3, cc = cell & 7;
      int kg = k0 + ((cc ^ (row & 7)) << 3);
      __builtin_amdgcn_global_load_lds(
        (const __attribute__((address_space(1))) void*)(Ab + (size_t)row*lda + kg),
        (__attribute__((address_space(3))) void*)(&sA[buf][cell<<3]), 16, 0, 0);
    }
  };

  // B bf16 [K][N]: 8 rows x 4 cols per thread, uint2 (8B) per row
  auto stageB_load = [&](int k0g, uint2* F){
    const __hip_bfloat16* p = Bb + (size_t)(k0g + (kq<<3))*ldn + n4;
    #pragma unroll
    for (int rr = 0; rr < 8; ++rr)
      F[rr] = *reinterpret_cast<const uint2*>(p + (size_t)rr*ldn);
  };
  auto stageB_write = [&](int buf, const uint2* F){
    #pragma unroll
    for (int j = 0; j < 4; ++j){
      int n = n4 + j;
      int cell = (kq ^ (n >> 3) ^ n) & 7;
      auto US = [&](int rr)->uint32_t{
        return (((const uint32_t*)&F[rr])[j >> 1] >> ((j & 1) * 16)) & 0xffffu;
      };
      uint4 d;
      d.x = US(0) | (US(1) << 16);
      d.y = US(2) | (US(3) << 16);
      d.z = US(4) | (US(5) << 16);
      d.w = US(6) | (US(7) << 16);
      *reinterpret_cast<uint4*>(&sB[buf][(n<<6) + (cell<<3)]) = d;
    }
  };

  uint2 F[8];
  stageB_load(kb, F);
  stageA(0, kb);
  stageB_write(0, F);
  __syncthreads();

  for (int t = 0; t < nk; ++t){
    if (t+1 < nk){
      stageB_load(kb + ((t+1)<<6), F);
      stageA((t+1)&1, kb + ((t+1)<<6));
    }
    const char* baseA = (const char*)(&sA[t&1][0]);
    const char* baseB = (const char*)(&sB[t&1][0]);
    int rA = (wr<<6) + (lane & 15);
    int rB = (wc<<6) + (lane & 15);
    #pragma unroll
    for (int kk = 0; kk < 2; ++kk){
      int koffA = ((((kk<<5) + ((lane>>4)<<3)) << 1)) ^ ((lane & 7) << 4);
      bf16x8 av[4], bv[4];
      #pragma unroll
      for (int f = 0; f < 4; ++f){
        int rowA = rA + f*16;
        av[f] = *reinterpret_cast<const bf16x8*>(baseA + (size_t)rowA*128 + koffA);
        int rowB = rB + f*16;
        int cellB = (((kk<<2) + (lane>>4)) ^ (rowB >> 3) ^ rowB) & 7;
        bv[f] = *reinterpret_cast<const bf16x8*>(baseB + (size_t)rowB*128 + (cellB<<4));
      }
      #pragma unroll
      for (int i = 0; i < 4; ++i)
        #pragma unroll
        for (int j = 0; j < 4; ++j)
          acc[i][j] = __builtin_amdgcn_mfma_f32_16x16x32_bf16(av[i], bv[j], acc[i][j], 0, 0, 0);
    }
    if (t+1 < nk) stageB_write((t+1)&1, F);
    __syncthreads();
  }

  // epilogue; C/D layout (m89-verified): col = lane&15, row = (lane>>4)*4 + reg
  #pragma unroll
  for (int i = 0; i < 4; ++i){
    int rbase = (mt<<7) + (wr<<6) + (i<<4) + ((lane>>4)<<2);
    #pragma unroll
    for (int j = 0; j < 4; ++j){
      int colp = (wc<<6) + (j<<4) + (lane & 15);
      #pragma unroll
      for (int qq = 0; qq < 4; ++qq){
        int r = rbase + qq;
        float v = acc[i][j][qq];
        if constexpr (EPI == EPI_SPLIT){
          int col = (nt<<7) + colp;
          outb[(size_t)kzi*pstride + (size_t)r*ldo + col] = __float2bfloat16(v);
        } else if constexpr (EPI == EPI_RES_BF16){
          int col = (nt<<7) + colp;
          int orig = rowmap[r];
          if (orig >= 0){
            v += bias[(size_t)s*biassub + col] + resid[(size_t)orig*ldres + col];
            outb[(size_t)r*ldo + col] = __float2bfloat16(v);
          }
        } else { // EPI_HEADS: bf16 partial (concat col space)
          int col = (ntl<<7) + colp;
          outb[(size_t)kzi*pstride + (size_t)r*ldo + col] = __float2bfloat16(v);
        }
      }
    }
  }
}

// ---------------- T1 = gelu(sum_p T1p + db[s])  (bf16 partials) ----------------
template<int NPART>
__global__ void t1_epilogue(const __hip_bfloat16* __restrict__ Tp, const float* __restrict__ db,
                            const int* __restrict__ rowmap, const int* __restrict__ tileS,
                            __hip_bfloat16* __restrict__ T1){
  int idx = blockIdx.x*256 + threadIdx.x;
  int r = idx >> 7, c = idx & 127;
  float v = 0.f;
  if (rowmap[r] >= 0){
    int s = tileS[r >> 7];
    float acc = 0.f;
    #pragma unroll
    for (int p = 0; p < NPART; ++p)
      acc += bf2f(*reinterpret_cast<const uint16_t*>(Tp + (size_t)p*MP*BOT + idx));
    v = gelu_exact(acc + db[s*BOT + c]);
  }
  T1[idx] = __float2bfloat16(v);
}

// ------- row LN over summed bf16 partials (+linear bias) + gelu (+bf16 residual) ------
// Residual state X lives ONLY in bf16 (Xb): halves LN IO vs fp32 Xf+bf16 Xb.
template<int RES, int NPART>
__global__ void ln_gelu_kernel(const __hip_bfloat16* __restrict__ Zp, size_t pstride,
                               const float* __restrict__ g,
                               const float* __restrict__ b, int gsub,
                               const float* __restrict__ lb,
                               const int* __restrict__ tileS, const int* __restrict__ rowmap,
                               __hip_bfloat16* __restrict__ Xb){
  int r = blockIdx.x, tid = threadIdx.x;
  size_t rowoff = (size_t)r * H;
  int c0 = tid << 3;
  int orig = rowmap[r];
  if (orig < 0){
    uint4 zu = {0u,0u,0u,0u};
    *reinterpret_cast<uint4*>(Xb + rowoff + c0) = zu;
    return;
  }
  int si = gsub ? tileS[r>>7] : 0;
  const float* gp  = g  + (size_t)si*gsub;
  const float* bp  = b  + (size_t)si*gsub;
  const float* lbp = lb + (size_t)si*gsub;
  float z[8];
  #pragma unroll
  for (int j = 0; j < 8; ++j) z[j] = lbp[c0+j];
  #pragma unroll
  for (int p = 0; p < NPART; ++p){
    uint4 v = *reinterpret_cast<const uint4*>(Zp + p*pstride + rowoff + c0);
    z[0] += bfu(v.x,0); z[1] += bfu(v.x,1);
    z[2] += bfu(v.y,0); z[3] += bfu(v.y,1);
    z[4] += bfu(v.z,0); z[5] += bfu(v.z,1);
    z[6] += bfu(v.w,0); z[7] += bfu(v.w,1);
  }
  float s1 = 0.f, s2 = 0.f;
  #pragma unroll
  for (int j = 0; j < 8; ++j){ s1 += z[j]; s2 += z[j]*z[j]; }
  #pragma unroll
  for (int m = 32; m >= 1; m >>= 1){ s1 += __shfl_xor(s1, m); s2 += __shfl_xor(s2, m); }
  __shared__ float red[4][2];
  int wv = tid >> 6, lane = tid & 63;
  if (lane == 0){ red[wv][0] = s1; red[wv][1] = s2; }
  __syncthreads();
  s1 = red[0][0]+red[1][0]+red[2][0]+red[3][0];
  s2 = red[0][1]+red[1][1]+red[2][1]+red[3][1];
  const float invH = 1.f / (float)H;
  float mu  = s1 * invH;
  float var = s2 * invH - mu*mu;
  float rs  = rsqrtf(var + 1e-5f);
  float o[8];
  #pragma unroll
  for (int j = 0; j < 8; ++j){
    float t = (z[j]-mu)*rs*gp[c0+j] + bp[c0+j];
    o[j] = gelu_exact(t);
  }
  if constexpr (RES){
    uint4 xv = *reinterpret_cast<const uint4*>(Xb + rowoff + c0);
    o[0] += bfu(xv.x,0); o[1] += bfu(xv.x,1);
    o[2] += bfu(xv.y,0); o[3] += bfu(xv.y,1);
    o[4] += bfu(xv.z,0); o[5] += bfu(xv.z,1);
    o[6] += bfu(xv.w,0); o[7] += bfu(xv.w,1);
  }
  __hip_bfloat16 ob[8];
  #pragma unroll
  for (int j = 0; j < 8; ++j) ob[j] = __float2bfloat16(o[j]);
  *reinterpret_cast<uint4*>(Xb + rowoff + c0) = *reinterpret_cast<const uint4*>(ob);
}

// ---------------- heads combine: sum 2 bf16 partials + bias, scatter -----------------
__global__ void head_combine(const __hip_bfloat16* __restrict__ Hp, size_t pstride,
                             const float* __restrict__ img_b, const float* __restrict__ txt_b,
                             const int* __restrict__ rowmap,
                             float* __restrict__ oimg, float* __restrict__ otxt){
  int r = blockIdx.x;
  int orig = rowmap[r];
  if (orig < 0) return;
  int col = threadIdx.x << 2;                    // 384 threads x 4 cols = 1536
  size_t base = (size_t)r*(IMG+TXT) + col;
  uint2 u0 = *reinterpret_cast<const uint2*>(Hp + base);
  uint2 u1 = *reinterpret_cast<const uint2*>(Hp + pstride + base);
  float4 acc;
  acc.x = bfu(u0.x,0) + bfu(u1.x,0);
  acc.y = bfu(u0.x,1) + bfu(u1.x,1);
  acc.z = bfu(u0.y,0) + bfu(u1.y,0);
  acc.w = bfu(u0.y,1) + bfu(u1.y,1);
  float4 bb = (col < IMG)
            ? *reinterpret_cast<const float4*>(img_b + col)
            : *reinterpret_cast<const float4*>(txt_b + (col - IMG));
  float4 o = {acc.x+bb.x, acc.y+bb.y, acc.z+bb.z, acc.w+bb.w};
  if (col < IMG) *reinterpret_cast<float4*>(oimg + (size_t)orig*IMG + col) = o;
  else           *reinterpret_cast<float4*>(otxt + (size_t)orig*TXT + (col-IMG)) = o;
}

// ------------------------------------------------------------------------------
extern "C" void kernel_launch(void* const* d_in, const int* in_sizes, int n_in,
                              void* d_out, int out_size, void* d_ws, size_t ws_size,
                              hipStream_t stream){
  (void)in_sizes; (void)n_in; (void)out_size; (void)ws_size;
  const float* vox       = (const float*)d_in[0];
  const int*   ids       = (const int*)  d_in[1];
  const float* ad_down_w = (const float*)d_in[2];
  const float* ad_down_b = (const float*)d_in[3];
  const float* ad_up_w   = (const float*)d_in[4];
  const float* ad_up_b   = (const float*)d_in[5];
  const float* enc_w     = (const float*)d_in[6];
  const float* enc_b     = (const float*)d_in[7];
  const float* enc_ln_g  = (const float*)d_in[8];
  const float* enc_ln_bb = (const float*)d_in[9];
  const float* bb_w      = (const float*)d_in[10];
  const float* bb_b      = (const float*)d_in[11];
  const float* bb_ln_g   = (const float*)d_in[12];
  const float* bb_ln_b   = (const float*)d_in[13];
  const float* img_w     = (const float*)d_in[14];
  const float* img_b     = (const float*)d_in[15];
  const float* txt_w     = (const float*)d_in[16];
  const float* txt_b     = (const float*)d_in[17];
  float* out = (float*)d_out;

  // bf16 weight pool segment sizes (elements)
  const size_t N_DOWN = (size_t)SUBJ*IN*BOT;
  const size_t N_UP   = (size_t)SUBJ*BOT*IN;
  const size_t N_ENC  = (size_t)SUBJ*IN*H;
  const size_t N_BB   = (size_t)DEPTH*H*H;
  const size_t N_IMG  = (size_t)H*IMG;
  const size_t N_TXT  = (size_t)H*TXT;

  char* wp = (char*)d_ws;
  auto alloc = [&](size_t bytes)->char*{ char* p = wp; wp += (bytes + 255) & ~(size_t)255; return p; };
  int* rowmap = (int*)alloc(MP * sizeof(int));
  int* tileS  = (int*)alloc(MT * sizeof(int));
  __hip_bfloat16* Wbf = (__hip_bfloat16*)alloc((N_DOWN+N_UP+N_ENC+N_BB+N_IMG+N_TXT)*2);
  __hip_bfloat16* w_down = Wbf;
  __hip_bfloat16* w_up   = w_down + N_DOWN;
  __hip_bfloat16* w_enc  = w_up   + N_UP;
  __hip_bfloat16* w_bb   = w_enc  + N_ENC;
  __hip_bfloat16* w_img  = w_bb   + N_BB;
  __hip_bfloat16* w_txt  = w_img  + N_IMG;
  __hip_bfloat16* Vs    = (__hip_bfloat16*)alloc((size_t)MP*IN*2);
  __hip_bfloat16* T1p   = (__hip_bfloat16*)alloc((size_t)32*MP*BOT*2);
  __hip_bfloat16* T1    = (__hip_bfloat16*)alloc((size_t)MP*BOT*2);
  __hip_bfloat16* Hs    = (__hip_bfloat16*)alloc((size_t)MP*IN*2);
  __hip_bfloat16* Zp    = (__hip_bfloat16*)alloc((size_t)4*MP*H*2);
  __hip_bfloat16* Hp    = Zp;               // alias: Zp dead before heads GEMM writes Hp
  __hip_bfloat16* Xb    = (__hip_bfloat16*)alloc((size_t)MP*H*2);

  const size_t ZPS = (size_t)MP*H;
  const size_t TPS = (size_t)MP*BOT;
  const size_t HPS = (size_t)MP*(IMG+TXT);

  // weight conversion pass (R13-best: 16 elem/thread, NT loads)
  CvtParams cp;
  size_t off = 0;
  cp.s[0] = {ad_down_w, off}; off += N_DOWN;
  cp.s[1] = {ad_up_w,   off}; off += N_UP;
  cp.s[2] = {enc_w,     off}; off += N_ENC;
  cp.s[3] = {bb_w,      off}; off += N_BB;
  cp.s[4] = {img_w,     off}; off += N_IMG;
  cp.s[5] = {txt_w,     off}; off += N_TXT;
  cp.total_items = off >> 4;                // 16 elements per item
  int cvt_blocks = (int)((cp.total_items + 255) / 256);
  convert_weights<<<cvt_blocks, 256, 0, stream>>>(cp, Wbf);

  sort_kernel<<<1, 1024, 0, stream>>>(ids, rowmap, tileS);
  gather_voxels<<<MP, 256, 0, stream>>>(vox, rowmap, Vs);

  // K1: adapter down. NT=1, KZ=32 (nx=1, qnt=1, ksplit=128, nk=2), grid 352 (R11 cfg).
  gemm_bf16<EPI_SPLIT,1><<<MT*32, 256, 0, stream>>>(
      Vs, IN, w_down, BOT, (long long)IN*BOT, tileS, rowmap, 1, 1, 128,
      nullptr, 0, nullptr, 0, T1p, BOT, TPS, nullptr);
  t1_epilogue<32><<<MP*BOT/256, 256, 0, stream>>>(T1p, ad_down_b, rowmap, tileS, T1);

  // K2: adapter up + residual. NT=32, KZ=1 (nx=8, qnt=4, ksplit=128), grid 352.
  gemm_bf16<EPI_RES_BF16,2><<<MT*32, 256, 0, stream>>>(
      T1, BOT, w_up, IN, (long long)BOT*IN, tileS, rowmap, 8, 4, 128,
      ad_up_b, IN, vox, IN, Hs, IN, 0, nullptr);

  // K3: encoder. NT=16, KZ=4 (nx=2, qnt=8, ksplit=1024, nk=16), grid 704.
  gemm_bf16<EPI_SPLIT,3><<<MT*8*8, 256, 0, stream>>>(
      Hs, IN, w_enc, H, (long long)IN*H, tileS, rowmap, 2, 8, 1024,
      nullptr, 0, nullptr, 0, Zp, H, ZPS, nullptr);
  ln_gelu_kernel<0,4><<<MP, 256, 0, stream>>>(Zp, ZPS, enc_ln_g, enc_ln_bb, H, enc_b,
                                              tileS, rowmap, Xb);

  // backbone: 6 x (NT=16, KZ=2 (nx=4, qnt=4, ksplit=1024), grid 352)
  for (int d = 0; d < DEPTH; ++d){
    gemm_bf16<EPI_SPLIT,4><<<MT*4*8, 256, 0, stream>>>(
        Xb, H, w_bb + (size_t)d*H*H, H, 0, tileS, rowmap, 4, 4, 1024,
        nullptr, 0, nullptr, 0, Zp, H, ZPS, nullptr);
    ln_gelu_kernel<1,2><<<MP, 256, 0, stream>>>(Zp, ZPS, bb_ln_g + (size_t)d*H,
                                                bb_ln_b + (size_t)d*H, 0, bb_b + (size_t)d*H,
                                                tileS, rowmap, Xb);
  }

  // heads: ONE gemm (img cols 0..5, txt 6..11), NT=12, KZ=2 (nx=4, qnt=3), grid 264.
  gemm_bf16<EPI_HEADS,5><<<MT*3*8, 256, 0, stream>>>(
      Xb, H, w_img, IMG, 0, tileS, rowmap, 4, 3, 1024,
      nullptr, 0, nullptr, 0, Hp, IMG+TXT, HPS, w_txt);
  head_combine<<<MP, 384, 0, stream>>>(Hp, HPS, img_b, txt_b, rowmap,
                                       out, out + (size_t)BATCH*IMG);
}